// Round 1
// baseline (5776.414 us; speedup 1.0000x reference)
//
#include <hip/hip_runtime.h>

#define D 128

// ---------------- degree / normalization ----------------
__global__ void k_init_deg(int* deg, int n) {
    int i = blockIdx.x * blockDim.x + threadIdx.x;
    if (i < n) deg[i] = 1;   // self loop
}

__global__ void k_count(const int* __restrict__ dst, int* deg, int e) {
    int i = blockIdx.x * blockDim.x + threadIdx.x;
    if (i < e) atomicAdd(&deg[dst[i]], 1);
}

__global__ void k_dis(const int* __restrict__ deg, float* dis, int n) {
    int i = blockIdx.x * blockDim.x + threadIdx.x;
    if (i < n) dis[i] = rsqrtf((float)deg[i]);
}

// ---------------- GEMM: H = X @ W^T + b  (fp32, LDS-tiled) ----------------
// block = 256 threads, tile = 128 rows x 128 cols, 8x8 outputs per thread
__global__ __launch_bounds__(256) void k_gemm(const float* __restrict__ X,
                                              const float* __restrict__ W,
                                              const float* __restrict__ B,
                                              float* __restrict__ H, int n) {
    __shared__ float Wt[D][132];   // Wt[k][j] = W[j][k]
    __shared__ float Xt[D][136];   // Xt[k][r] = X[row0+r][k]
    const int t = threadIdx.x;
    const int row0 = blockIdx.x * 128;

    #pragma unroll
    for (int i = 0; i < 64; ++i) {          // 16384 W elems
        int idx = t + i * 256;
        int j = idx >> 7, k = idx & 127;
        Wt[k][j] = W[idx];
    }
    #pragma unroll
    for (int i = 0; i < 64; ++i) {          // 16384 X elems (transposed)
        int idx = t + i * 256;
        int r = idx >> 7, k = idx & 127;
        int row = row0 + r;
        Xt[k][r] = (row < n) ? X[(size_t)row * D + k] : 0.0f;
    }
    __syncthreads();

    const int j0 = (t & 15) * 8;
    const int r0 = (t >> 4) * 8;
    float acc[8][8];
    #pragma unroll
    for (int r = 0; r < 8; ++r)
        #pragma unroll
        for (int c = 0; c < 8; ++c) acc[r][c] = 0.f;

    for (int k = 0; k < D; ++k) {
        float4 wa = *(const float4*)&Wt[k][j0];
        float4 wb = *(const float4*)&Wt[k][j0 + 4];
        float4 xa = *(const float4*)&Xt[k][r0];
        float4 xb = *(const float4*)&Xt[k][r0 + 4];
        float w[8]  = {wa.x, wa.y, wa.z, wa.w, wb.x, wb.y, wb.z, wb.w};
        float xr[8] = {xa.x, xa.y, xa.z, xa.w, xb.x, xb.y, xb.z, xb.w};
        #pragma unroll
        for (int r = 0; r < 8; ++r)
            #pragma unroll
            for (int c = 0; c < 8; ++c)
                acc[r][c] = fmaf(xr[r], w[c], acc[r][c]);
    }

    float bj[8];
    #pragma unroll
    for (int c = 0; c < 8; ++c) bj[c] = B[j0 + c];
    #pragma unroll
    for (int r = 0; r < 8; ++r) {
        int row = row0 + r0 + r;
        if (row < n) {
            float4 o0 = make_float4(acc[r][0] + bj[0], acc[r][1] + bj[1],
                                    acc[r][2] + bj[2], acc[r][3] + bj[3]);
            float4 o1 = make_float4(acc[r][4] + bj[4], acc[r][5] + bj[5],
                                    acc[r][6] + bj[6], acc[r][7] + bj[7]);
            *(float4*)&H[(size_t)row * D + j0]     = o0;
            *(float4*)&H[(size_t)row * D + j0 + 4] = o1;
        }
    }
}

// ---------------- self-loop init: O[i][d] = H[i][d] * dis[i]^2 ----------------
__global__ void k_selfinit(const float* __restrict__ H, const float* __restrict__ dis,
                           float* __restrict__ O, int n) {
    int total = n * (D / 4);
    for (int idx = blockIdx.x * blockDim.x + threadIdx.x; idx < total;
         idx += gridDim.x * blockDim.x) {
        int i = idx >> 5;              // 32 float4 per row
        float s = dis[i]; s = s * s;
        float4 h = ((const float4*)H)[idx];
        ((float4*)O)[idx] = make_float4(h.x * s, h.y * s, h.z * s, h.w * s);
    }
}

// ---------------- edge scatter: O[dst] += H[src] * dis[src]*dis[dst] ----------------
__global__ void k_scatter(const float* __restrict__ H, const int* __restrict__ src,
                          const int* __restrict__ dst, const float* __restrict__ dis,
                          float* O, int e) {
    long long total = (long long)e * 32;   // float4 granules
    for (long long idx = blockIdx.x * (long long)blockDim.x + threadIdx.x; idx < total;
         idx += (long long)gridDim.x * blockDim.x) {
        int ed = (int)(idx >> 5);
        int q  = (int)(idx & 31);
        int s  = src[ed], tn = dst[ed];
        float w = dis[s] * dis[tn];
        float4 h = ((const float4*)(H + (size_t)s * D))[q];
        float* o = O + (size_t)tn * D + q * 4;
        atomicAdd(o + 0, h.x * w);
        atomicAdd(o + 1, h.y * w);
        atomicAdd(o + 2, h.z * w);
        atomicAdd(o + 3, h.w * w);
    }
}

// ---------------- PReLU in place ----------------
__global__ void k_prelu(float* Y, const float* __restrict__ a, int total4) {
    float al = a[0];
    for (int idx = blockIdx.x * blockDim.x + threadIdx.x; idx < total4;
         idx += gridDim.x * blockDim.x) {
        float4 v = ((float4*)Y)[idx];
        v.x = v.x > 0.f ? v.x : al * v.x;
        v.y = v.y > 0.f ? v.y : al * v.y;
        v.z = v.z > 0.f ? v.z : al * v.z;
        v.w = v.w > 0.f ? v.w : al * v.w;
        ((float4*)Y)[idx] = v;
    }
}

extern "C" void kernel_launch(void* const* d_in, const int* in_sizes, int n_in,
                              void* d_out, int out_size, void* d_ws, size_t ws_size,
                              hipStream_t stream) {
    const float* x  = (const float*)d_in[0];
    const int*   ei = (const int*)d_in[1];
    const float* W1 = (const float*)d_in[2];
    const float* b1 = (const float*)d_in[3];
    const float* a1 = (const float*)d_in[4];
    const float* W2 = (const float*)d_in[5];
    const float* b2 = (const float*)d_in[6];
    const float* a2 = (const float*)d_in[7];

    const int n = in_sizes[0] / D;
    const int e = in_sizes[1] / 2;
    const int* srcv = ei;
    const int* dstv = ei + e;

    char* ws = (char*)d_ws;
    size_t off = 0;
    auto alloc = [&](size_t bytes) {
        void* p = ws + off;
        off = (off + bytes + 255) & ~(size_t)255;
        return p;
    };
    int*   deg  = (int*)  alloc((size_t)n * 4);
    float* dis  = (float*)alloc((size_t)n * 4);
    float* bufA = (float*)alloc((size_t)n * D * 4);
    float* bufB = (float*)alloc((size_t)n * D * 4);
    float* out  = (float*)d_out;

    dim3 blk(256);
    k_init_deg<<<(n + 255) / 256, blk, 0, stream>>>(deg, n);
    k_count   <<<(e + 255) / 256, blk, 0, stream>>>(dstv, deg, e);
    k_dis     <<<(n + 255) / 256, blk, 0, stream>>>(deg, dis, n);

    // layer 1
    k_gemm    <<<(n + 127) / 128, blk, 0, stream>>>(x, W1, b1, bufA, n);
    k_selfinit<<<2048, blk, 0, stream>>>(bufA, dis, bufB, n);
    k_scatter <<<4096, blk, 0, stream>>>(bufA, srcv, dstv, dis, bufB, e);
    k_prelu   <<<2048, blk, 0, stream>>>(bufB, a1, n * (D / 4));

    // layer 2
    k_gemm    <<<(n + 127) / 128, blk, 0, stream>>>(bufB, W2, b2, bufA, n);
    k_selfinit<<<2048, blk, 0, stream>>>(bufA, dis, out, n);
    k_scatter <<<4096, blk, 0, stream>>>(bufA, srcv, dstv, dis, out, e);
    k_prelu   <<<2048, blk, 0, stream>>>(out, a2, n * (D / 4));
}

// Round 2
// 794.995 us; speedup vs baseline: 7.2660x; 7.2660x over previous
//
#include <hip/hip_runtime.h>

#define D 128

// ---------------- degree / normalization ----------------
__global__ void k_init_deg(int* deg, int n) {
    int i = blockIdx.x * blockDim.x + threadIdx.x;
    if (i < n) deg[i] = 1;   // self loop
}

__global__ void k_count(const int* __restrict__ dst, int* deg, int e) {
    int i = blockIdx.x * blockDim.x + threadIdx.x;
    if (i < e) atomicAdd(&deg[dst[i]], 1);
}

__global__ void k_dis(const int* __restrict__ deg, float* dis, int n) {
    int i = blockIdx.x * blockDim.x + threadIdx.x;
    if (i < n) dis[i] = rsqrtf((float)deg[i]);
}

// ---------------- CSR build: exclusive scan of indegree (deg-1) ----------------
__global__ __launch_bounds__(256) void k_scan1(const int* __restrict__ deg, int* rowptr,
                                               int* bsum, int n) {
    __shared__ int sd[256];
    int t = threadIdx.x;
    int base = blockIdx.x * 1024 + t * 4;
    int v[4];
    #pragma unroll
    for (int j = 0; j < 4; ++j) {
        int idx = base + j;
        v[j] = (idx < n) ? (deg[idx] - 1) : 0;
    }
    int s = v[0] + v[1] + v[2] + v[3];
    sd[t] = s;
    __syncthreads();
    for (int off = 1; off < 256; off <<= 1) {
        int x = (t >= off) ? sd[t - off] : 0;
        __syncthreads();
        sd[t] += x;
        __syncthreads();
    }
    int p = sd[t] - s;   // exclusive prefix of this thread's quad
    #pragma unroll
    for (int j = 0; j < 4; ++j) {
        int idx = base + j;
        if (idx < n) rowptr[idx] = p;
        p += v[j];
    }
    if (t == 255) bsum[blockIdx.x] = sd[255];
}

__global__ void k_scan2(int* bsum, int nb) {
    __shared__ int sd[256];
    int t = threadIdx.x;
    int s = (t < nb) ? bsum[t] : 0;
    sd[t] = s;
    __syncthreads();
    for (int off = 1; off < 256; off <<= 1) {
        int x = (t >= off) ? sd[t - off] : 0;
        __syncthreads();
        sd[t] += x;
        __syncthreads();
    }
    if (t < nb) bsum[t] = sd[t] - s;   // exclusive
}

__global__ void k_scan3(int* rowptr, const int* __restrict__ bsum, int n, int e) {
    int i = blockIdx.x * blockDim.x + threadIdx.x;
    if (i < n) rowptr[i] += bsum[i >> 10];
    if (i == 0) rowptr[n] = e;
}

__global__ void k_fill(const int* __restrict__ srcv, const int* __restrict__ dstv,
                       const int* __restrict__ rowptr, int* cur, int* csr_src, int e) {
    int i = blockIdx.x * blockDim.x + threadIdx.x;
    if (i < e) {
        int d = dstv[i];
        int pos = atomicAdd(&cur[d], 1);
        csr_src[rowptr[d] + pos] = srcv[i];
    }
}

// ---------------- GEMM: G = (X @ W^T + b) * dis[row]  (fp32, LDS-tiled) ----------------
// Safe to run in-place (H == X): each block reads only its own 128 rows into LDS
// (completed before the writes) and writes only those rows.
__global__ __launch_bounds__(256) void k_gemm(const float* __restrict__ X,
                                              const float* __restrict__ W,
                                              const float* __restrict__ B,
                                              const float* __restrict__ dis,
                                              float* __restrict__ H, int n) {
    __shared__ float Wt[D][132];   // Wt[k][j] = W[j][k]
    __shared__ float Xt[D][136];   // Xt[k][r] = X[row0+r][k]
    const int t = threadIdx.x;
    const int row0 = blockIdx.x * 128;

    #pragma unroll
    for (int i = 0; i < 64; ++i) {          // 16384 W elems
        int idx = t + i * 256;
        int j = idx >> 7, k = idx & 127;
        Wt[k][j] = W[idx];
    }
    #pragma unroll
    for (int i = 0; i < 64; ++i) {          // 16384 X elems (transposed)
        int idx = t + i * 256;
        int r = idx >> 7, k = idx & 127;
        int row = row0 + r;
        Xt[k][r] = (row < n) ? X[(size_t)row * D + k] : 0.0f;
    }
    __syncthreads();

    const int j0 = (t & 15) * 8;
    const int r0 = (t >> 4) * 8;
    float acc[8][8];
    #pragma unroll
    for (int r = 0; r < 8; ++r)
        #pragma unroll
        for (int c = 0; c < 8; ++c) acc[r][c] = 0.f;

    for (int k = 0; k < D; ++k) {
        float4 wa = *(const float4*)&Wt[k][j0];
        float4 wb = *(const float4*)&Wt[k][j0 + 4];
        float4 xa = *(const float4*)&Xt[k][r0];
        float4 xb = *(const float4*)&Xt[k][r0 + 4];
        float w[8]  = {wa.x, wa.y, wa.z, wa.w, wb.x, wb.y, wb.z, wb.w};
        float xr[8] = {xa.x, xa.y, xa.z, xa.w, xb.x, xb.y, xb.z, xb.w};
        #pragma unroll
        for (int r = 0; r < 8; ++r)
            #pragma unroll
            for (int c = 0; c < 8; ++c)
                acc[r][c] = fmaf(xr[r], w[c], acc[r][c]);
    }

    float bj[8];
    #pragma unroll
    for (int c = 0; c < 8; ++c) bj[c] = B[j0 + c];
    #pragma unroll
    for (int r = 0; r < 8; ++r) {
        int row = row0 + r0 + r;
        if (row < n) {
            float ds = dis[row];
            float4 o0 = make_float4((acc[r][0] + bj[0]) * ds, (acc[r][1] + bj[1]) * ds,
                                    (acc[r][2] + bj[2]) * ds, (acc[r][3] + bj[3]) * ds);
            float4 o1 = make_float4((acc[r][4] + bj[4]) * ds, (acc[r][5] + bj[5]) * ds,
                                    (acc[r][6] + bj[6]) * ds, (acc[r][7] + bj[7]) * ds);
            *(float4*)&H[(size_t)row * D + j0]     = o0;
            *(float4*)&H[(size_t)row * D + j0 + 4] = o1;
        }
    }
}

// ---------------- gather-aggregate + self loop + PReLU ----------------
// out[i] = prelu( dis[i] * ( G[i] + sum_{src->i} G[src] ) )
// one 64-lane wave per destination node; each lane owns 2 floats of the row
__global__ __launch_bounds__(256) void k_gather(const float* __restrict__ G,
                                                const float* __restrict__ dis,
                                                const int* __restrict__ rowptr,
                                                const int* __restrict__ csr_src,
                                                const float* __restrict__ a,
                                                float* __restrict__ O, int n) {
    int wid = (blockIdx.x * 256 + threadIdx.x) >> 6;
    if (wid >= n) return;
    int lane = threadIdx.x & 63;
    const float2* Gv = (const float2*)G;
    float2 acc = Gv[(size_t)wid * 64 + lane];        // self contribution
    int e0 = rowptr[wid], e1 = rowptr[wid + 1];
    for (int e = e0; e < e1; ++e) {
        int s = csr_src[e];
        float2 g = Gv[(size_t)s * 64 + lane];
        acc.x += g.x;
        acc.y += g.y;
    }
    float dsc = dis[wid];
    float al = a[0];
    float vx = acc.x * dsc, vy = acc.y * dsc;
    vx = vx > 0.f ? vx : al * vx;
    vy = vy > 0.f ? vy : al * vy;
    ((float2*)O)[(size_t)wid * 64 + lane] = make_float2(vx, vy);
}

extern "C" void kernel_launch(void* const* d_in, const int* in_sizes, int n_in,
                              void* d_out, int out_size, void* d_ws, size_t ws_size,
                              hipStream_t stream) {
    const float* x  = (const float*)d_in[0];
    const int*   ei = (const int*)d_in[1];
    const float* W1 = (const float*)d_in[2];
    const float* b1 = (const float*)d_in[3];
    const float* a1 = (const float*)d_in[4];
    const float* W2 = (const float*)d_in[5];
    const float* b2 = (const float*)d_in[6];
    const float* a2 = (const float*)d_in[7];

    const int n = in_sizes[0] / D;
    const int e = in_sizes[1] / 2;
    const int* srcv = ei;
    const int* dstv = ei + e;

    char* ws = (char*)d_ws;
    size_t off = 0;
    auto alloc = [&](size_t bytes) {
        void* p = ws + off;
        off = (off + bytes + 255) & ~(size_t)255;
        return p;
    };
    int*   deg     = (int*)  alloc((size_t)n * 4);
    float* dis     = (float*)alloc((size_t)n * 4);
    int*   rowptr  = (int*)  alloc((size_t)(n + 1) * 4);
    int*   cur     = (int*)  alloc((size_t)n * 4);
    int*   bsum    = (int*)  alloc(1024);
    int*   csr_src = (int*)  alloc((size_t)e * 4);
    float* bufA    = (float*)alloc((size_t)n * D * 4);
    size_t need_second = off + (size_t)n * D * 4;
    bool   twoBuf = (ws_size >= need_second);
    float* bufB = twoBuf ? (float*)alloc((size_t)n * D * 4) : nullptr;
    float* out  = (float*)d_out;

    dim3 blk(256);
    const int nb = (n + 1023) / 1024;

    k_init_deg<<<(n + 255) / 256, blk, 0, stream>>>(deg, n);
    k_count   <<<(e + 255) / 256, blk, 0, stream>>>(dstv, deg, e);
    k_dis     <<<(n + 255) / 256, blk, 0, stream>>>(deg, dis, n);
    k_scan1   <<<nb, blk, 0, stream>>>(deg, rowptr, bsum, n);
    k_scan2   <<<1, blk, 0, stream>>>(bsum, nb);
    k_scan3   <<<(n + 255) / 256, blk, 0, stream>>>(rowptr, bsum, n, e);
    hipMemsetAsync(cur, 0, (size_t)n * 4, stream);
    k_fill    <<<(e + 255) / 256, blk, 0, stream>>>(srcv, dstv, rowptr, cur, csr_src, e);

    const int gat_grid = (n * 64 + 255) / 256;   // one wave per node

    if (twoBuf) {
        // layer 1: x -> g1(bufA) -> h1(bufB)
        k_gemm  <<<(n + 127) / 128, blk, 0, stream>>>(x, W1, b1, dis, bufA, n);
        k_gather<<<gat_grid, blk, 0, stream>>>(bufA, dis, rowptr, csr_src, a1, bufB, n);
        // layer 2: h1(bufB) -> g2(bufB, in-place) -> out
        k_gemm  <<<(n + 127) / 128, blk, 0, stream>>>(bufB, W2, b2, dis, bufB, n);
        k_gather<<<gat_grid, blk, 0, stream>>>(bufB, dis, rowptr, csr_src, a2, out, n);
    } else {
        // layer 1: x -> g1(bufA) -> h1(d_out as temp)
        k_gemm  <<<(n + 127) / 128, blk, 0, stream>>>(x, W1, b1, dis, bufA, n);
        k_gather<<<gat_grid, blk, 0, stream>>>(bufA, dis, rowptr, csr_src, a1, out, n);
        // layer 2: h1(d_out) -> g2(d_out, in-place) -> bufA -> copy to d_out
        k_gemm  <<<(n + 127) / 128, blk, 0, stream>>>(out, W2, b2, dis, out, n);
        k_gather<<<gat_grid, blk, 0, stream>>>(out, dis, rowptr, csr_src, a2, bufA, n);
        hipMemcpyAsync(d_out, bufA, (size_t)n * D * 4, hipMemcpyDeviceToDevice, stream);
    }
}

// Round 3
// 538.951 us; speedup vs baseline: 10.7179x; 1.4751x over previous
//
#include <hip/hip_runtime.h>

#define D 128
#define KC 32

// ---------------- degree / normalization ----------------
__global__ void k_init_deg(int* deg, int n) {
    int i = blockIdx.x * blockDim.x + threadIdx.x;
    if (i < n) deg[i] = 1;   // self loop
}

__global__ void k_count(const int* __restrict__ dst, int* deg, int e) {
    int i = blockIdx.x * blockDim.x + threadIdx.x;
    if (i < e) atomicAdd(&deg[dst[i]], 1);
}

__global__ void k_dis(const int* __restrict__ deg, float* dis, int n) {
    int i = blockIdx.x * blockDim.x + threadIdx.x;
    if (i < n) dis[i] = rsqrtf((float)deg[i]);
}

// ---------------- CSR build: exclusive scan of indegree (deg-1) ----------------
__global__ __launch_bounds__(256) void k_scan1(const int* __restrict__ deg, int* rowptr,
                                               int* bsum, int n) {
    __shared__ int sd[256];
    int t = threadIdx.x;
    int base = blockIdx.x * 1024 + t * 4;
    int v[4];
    #pragma unroll
    for (int j = 0; j < 4; ++j) {
        int idx = base + j;
        v[j] = (idx < n) ? (deg[idx] - 1) : 0;
    }
    int s = v[0] + v[1] + v[2] + v[3];
    sd[t] = s;
    __syncthreads();
    for (int off = 1; off < 256; off <<= 1) {
        int x = (t >= off) ? sd[t - off] : 0;
        __syncthreads();
        sd[t] += x;
        __syncthreads();
    }
    int p = sd[t] - s;   // exclusive prefix of this thread's quad
    #pragma unroll
    for (int j = 0; j < 4; ++j) {
        int idx = base + j;
        if (idx < n) rowptr[idx] = p;
        p += v[j];
    }
    if (t == 255) bsum[blockIdx.x] = sd[255];
}

__global__ void k_scan2(int* bsum, int nb) {
    __shared__ int sd[256];
    int t = threadIdx.x;
    int s = (t < nb) ? bsum[t] : 0;
    sd[t] = s;
    __syncthreads();
    for (int off = 1; off < 256; off <<= 1) {
        int x = (t >= off) ? sd[t - off] : 0;
        __syncthreads();
        sd[t] += x;
        __syncthreads();
    }
    if (t < nb) bsum[t] = sd[t] - s;   // exclusive
}

__global__ void k_scan3(int* rowptr, const int* __restrict__ bsum, int n, int e) {
    int i = blockIdx.x * blockDim.x + threadIdx.x;
    if (i < n) rowptr[i] += bsum[i >> 10];
    if (i == 0) rowptr[n] = e;
}

__global__ void k_fill(const int* __restrict__ srcv, const int* __restrict__ dstv,
                       const int* __restrict__ rowptr, int* cur, int* csr_src, int e) {
    int i = blockIdx.x * blockDim.x + threadIdx.x;
    if (i < e) {
        int d = dstv[i];
        int pos = atomicAdd(&cur[d], 1);
        csr_src[rowptr[d] + pos] = srcv[i];
    }
}

// ---------------- GEMM: G = (X @ W^T + b) * dis[row] ----------------
// block = 512 threads, tile 128 rows x 128 cols, K chunked by 32 (single LDS buffer,
// 33.8 KB -> multiple blocks/CU). Thread: 8 rows x 4 cols.
// In-place safe (H == X): block reads only its own 128 rows, writes them after all
// chunk reads complete.
__global__ __launch_bounds__(512, 4) void k_gemm(const float* __restrict__ X,
                                                 const float* __restrict__ W,
                                                 const float* __restrict__ B,
                                                 const float* __restrict__ dis,
                                                 float* __restrict__ H, int n) {
    __shared__ float Wt[KC][132];   // Wt[k][j] = W[j][kc+k]
    __shared__ float Xt[KC][132];   // Xt[k][r] = X[row0+r][kc+k]
    const int t = threadIdx.x;
    const int row0 = blockIdx.x * 128;
    const int j0 = (t & 31) * 4;
    const int r0 = (t >> 5) * 8;

    const float4* X4 = (const float4*)X;
    const float4* W4 = (const float4*)W;

    float acc[8][4];
    #pragma unroll
    for (int r = 0; r < 8; ++r)
        #pragma unroll
        for (int c = 0; c < 4; ++c) acc[r][c] = 0.f;

    const int srow = t >> 3;        // 0..63
    const int skq  = t & 7;         // 0..7

    #pragma unroll 1
    for (int kc = 0; kc < D; kc += KC) {
        // ---- stage X and W chunks (transposed) ----
        #pragma unroll
        for (int i = 0; i < 2; ++i) {
            int row = srow + i * 64;
            float4 xv = make_float4(0.f, 0.f, 0.f, 0.f);
            int grow = row0 + row;
            if (grow < n) xv = X4[(size_t)grow * 32 + (kc >> 2) + skq];
            Xt[skq * 4 + 0][row] = xv.x;
            Xt[skq * 4 + 1][row] = xv.y;
            Xt[skq * 4 + 2][row] = xv.z;
            Xt[skq * 4 + 3][row] = xv.w;
            float4 wv = W4[(size_t)row * 32 + (kc >> 2) + skq];   // row == output col j
            Wt[skq * 4 + 0][row] = wv.x;
            Wt[skq * 4 + 1][row] = wv.y;
            Wt[skq * 4 + 2][row] = wv.z;
            Wt[skq * 4 + 3][row] = wv.w;
        }
        __syncthreads();

        // ---- compute ----
        #pragma unroll 2
        for (int kg = 0; kg < KC; kg += 4) {
            float4 w[4], xa[4], xb[4];
            #pragma unroll
            for (int kk = 0; kk < 4; ++kk) {
                w[kk]  = *(const float4*)&Wt[kg + kk][j0];
                xa[kk] = *(const float4*)&Xt[kg + kk][r0];
                xb[kk] = *(const float4*)&Xt[kg + kk][r0 + 4];
            }
            #pragma unroll
            for (int kk = 0; kk < 4; ++kk) {
                float xr[8] = {xa[kk].x, xa[kk].y, xa[kk].z, xa[kk].w,
                               xb[kk].x, xb[kk].y, xb[kk].z, xb[kk].w};
                #pragma unroll
                for (int r = 0; r < 8; ++r) {
                    acc[r][0] = fmaf(xr[r], w[kk].x, acc[r][0]);
                    acc[r][1] = fmaf(xr[r], w[kk].y, acc[r][1]);
                    acc[r][2] = fmaf(xr[r], w[kk].z, acc[r][2]);
                    acc[r][3] = fmaf(xr[r], w[kk].w, acc[r][3]);
                }
            }
        }
        __syncthreads();
    }

    // ---- epilogue: bias, dis scale, store ----
    float4 bj = *(const float4*)&B[j0];
    #pragma unroll
    for (int r = 0; r < 8; ++r) {
        int row = row0 + r0 + r;
        if (row < n) {
            float ds = dis[row];
            float4 o = make_float4((acc[r][0] + bj.x) * ds, (acc[r][1] + bj.y) * ds,
                                   (acc[r][2] + bj.z) * ds, (acc[r][3] + bj.w) * ds);
            *(float4*)&H[(size_t)row * D + j0] = o;
        }
    }
}

// ---------------- gather-aggregate + self loop + PReLU ----------------
// out[i] = prelu( dis[i] * ( G[i] + sum_{src->i} G[src] ) )
// one 64-lane wave per destination node; each lane owns 2 floats of the row
__global__ __launch_bounds__(256) void k_gather(const float* __restrict__ G,
                                                const float* __restrict__ dis,
                                                const int* __restrict__ rowptr,
                                                const int* __restrict__ csr_src,
                                                const float* __restrict__ a,
                                                float* __restrict__ O, int n) {
    int wid = (blockIdx.x * 256 + threadIdx.x) >> 6;
    if (wid >= n) return;
    int lane = threadIdx.x & 63;
    const float2* Gv = (const float2*)G;
    float2 acc = Gv[(size_t)wid * 64 + lane];        // self contribution
    int e = rowptr[wid], e1 = rowptr[wid + 1];
    for (; e + 4 <= e1; e += 4) {
        int s0 = csr_src[e + 0];
        int s1 = csr_src[e + 1];
        int s2 = csr_src[e + 2];
        int s3 = csr_src[e + 3];
        float2 g0 = Gv[(size_t)s0 * 64 + lane];
        float2 g1 = Gv[(size_t)s1 * 64 + lane];
        float2 g2 = Gv[(size_t)s2 * 64 + lane];
        float2 g3 = Gv[(size_t)s3 * 64 + lane];
        acc.x += g0.x + g1.x + g2.x + g3.x;
        acc.y += g0.y + g1.y + g2.y + g3.y;
    }
    for (; e < e1; ++e) {
        int s = csr_src[e];
        float2 g = Gv[(size_t)s * 64 + lane];
        acc.x += g.x;
        acc.y += g.y;
    }
    float dsc = dis[wid];
    float al = a[0];
    float vx = acc.x * dsc, vy = acc.y * dsc;
    vx = vx > 0.f ? vx : al * vx;
    vy = vy > 0.f ? vy : al * vy;
    ((float2*)O)[(size_t)wid * 64 + lane] = make_float2(vx, vy);
}

extern "C" void kernel_launch(void* const* d_in, const int* in_sizes, int n_in,
                              void* d_out, int out_size, void* d_ws, size_t ws_size,
                              hipStream_t stream) {
    const float* x  = (const float*)d_in[0];
    const int*   ei = (const int*)d_in[1];
    const float* W1 = (const float*)d_in[2];
    const float* b1 = (const float*)d_in[3];
    const float* a1 = (const float*)d_in[4];
    const float* W2 = (const float*)d_in[5];
    const float* b2 = (const float*)d_in[6];
    const float* a2 = (const float*)d_in[7];

    const int n = in_sizes[0] / D;
    const int e = in_sizes[1] / 2;
    const int* srcv = ei;
    const int* dstv = ei + e;

    char* ws = (char*)d_ws;
    size_t off = 0;
    auto alloc = [&](size_t bytes) {
        void* p = ws + off;
        off = (off + bytes + 255) & ~(size_t)255;
        return p;
    };
    int*   deg     = (int*)  alloc((size_t)n * 4);
    float* dis     = (float*)alloc((size_t)n * 4);
    int*   rowptr  = (int*)  alloc((size_t)(n + 1) * 4);
    int*   cur     = (int*)  alloc((size_t)n * 4);
    int*   bsum    = (int*)  alloc(1024);
    int*   csr_src = (int*)  alloc((size_t)e * 4);
    float* bufA    = (float*)alloc((size_t)n * D * 4);
    size_t need_second = off + (size_t)n * D * 4;
    bool   twoBuf = (ws_size >= need_second);
    float* bufB = twoBuf ? (float*)alloc((size_t)n * D * 4) : nullptr;
    float* out  = (float*)d_out;

    dim3 blk(256);
    const int nb = (n + 1023) / 1024;

    k_init_deg<<<(n + 255) / 256, blk, 0, stream>>>(deg, n);
    k_count   <<<(e + 255) / 256, blk, 0, stream>>>(dstv, deg, e);
    k_dis     <<<(n + 255) / 256, blk, 0, stream>>>(deg, dis, n);
    k_scan1   <<<nb, blk, 0, stream>>>(deg, rowptr, bsum, n);
    k_scan2   <<<1, blk, 0, stream>>>(bsum, nb);
    k_scan3   <<<(n + 255) / 256, blk, 0, stream>>>(rowptr, bsum, n, e);
    hipMemsetAsync(cur, 0, (size_t)n * 4, stream);
    k_fill    <<<(e + 255) / 256, blk, 0, stream>>>(srcv, dstv, rowptr, cur, csr_src, e);

    const int gat_grid = (n * 64 + 255) / 256;   // one wave per node
    const int gemm_grid = (n + 127) / 128;

    if (twoBuf) {
        // layer 1: x -> g1(bufA) -> h1(bufB)
        k_gemm  <<<gemm_grid, 512, 0, stream>>>(x, W1, b1, dis, bufA, n);
        k_gather<<<gat_grid, blk, 0, stream>>>(bufA, dis, rowptr, csr_src, a1, bufB, n);
        // layer 2: h1(bufB) -> g2(bufB, in-place) -> out
        k_gemm  <<<gemm_grid, 512, 0, stream>>>(bufB, W2, b2, dis, bufB, n);
        k_gather<<<gat_grid, blk, 0, stream>>>(bufB, dis, rowptr, csr_src, a2, out, n);
    } else {
        // layer 1: x -> g1(bufA) -> h1(d_out as temp)
        k_gemm  <<<gemm_grid, 512, 0, stream>>>(x, W1, b1, dis, bufA, n);
        k_gather<<<gat_grid, blk, 0, stream>>>(bufA, dis, rowptr, csr_src, a1, out, n);
        // layer 2: h1(d_out) -> g2(d_out, in-place) -> bufA -> copy to d_out
        k_gemm  <<<gemm_grid, 512, 0, stream>>>(out, W2, b2, dis, out, n);
        k_gather<<<gat_grid, blk, 0, stream>>>(out, dis, rowptr, csr_src, a2, bufA, n);
        hipMemcpyAsync(d_out, bufA, (size_t)n * D * 4, hipMemcpyDeviceToDevice, stream);
    }
}

// Round 4
// 459.328 us; speedup vs baseline: 12.5758x; 1.1733x over previous
//
#include <hip/hip_runtime.h>
#include <hip/hip_fp16.h>

#define D 128
#define KC 32

// ---------------- degree / normalization ----------------
__global__ void k_count(const int* __restrict__ dst, int* deg, int e) {
    int i = blockIdx.x * blockDim.x + threadIdx.x;
    if (i < e) atomicAdd(&deg[dst[i]], 1);
}

__global__ void k_dis(const int* __restrict__ deg, float* dis, int n) {
    int i = blockIdx.x * blockDim.x + threadIdx.x;
    if (i < n) dis[i] = rsqrtf((float)(deg[i] + 1));   // +1 self loop
}

// ---------------- CSR build: exclusive scan of indegree ----------------
__global__ __launch_bounds__(256) void k_scan1(const int* __restrict__ deg, int* rowptr,
                                               int* bsum, int n) {
    __shared__ int sd[256];
    int t = threadIdx.x;
    int base = blockIdx.x * 1024 + t * 4;
    int v[4];
    #pragma unroll
    for (int j = 0; j < 4; ++j) {
        int idx = base + j;
        v[j] = (idx < n) ? deg[idx] : 0;
    }
    int s = v[0] + v[1] + v[2] + v[3];
    sd[t] = s;
    __syncthreads();
    for (int off = 1; off < 256; off <<= 1) {
        int x = (t >= off) ? sd[t - off] : 0;
        __syncthreads();
        sd[t] += x;
        __syncthreads();
    }
    int p = sd[t] - s;   // exclusive prefix of this thread's quad
    #pragma unroll
    for (int j = 0; j < 4; ++j) {
        int idx = base + j;
        if (idx < n) rowptr[idx] = p;
        p += v[j];
    }
    if (t == 255) bsum[blockIdx.x] = sd[255];
}

__global__ void k_scan2(int* bsum, int nb) {
    __shared__ int sd[256];
    int t = threadIdx.x;
    int s = (t < nb) ? bsum[t] : 0;
    sd[t] = s;
    __syncthreads();
    for (int off = 1; off < 256; off <<= 1) {
        int x = (t >= off) ? sd[t - off] : 0;
        __syncthreads();
        sd[t] += x;
        __syncthreads();
    }
    if (t < nb) bsum[t] = sd[t] - s;   // exclusive
}

__global__ void k_scan3(int* rowptr, int* rowwork, const int* __restrict__ bsum,
                        int n, int e) {
    int i = blockIdx.x * blockDim.x + threadIdx.x;
    if (i < n) {
        int v = rowptr[i] + bsum[i >> 10];
        rowptr[i] = v;
        rowwork[i] = v;
    }
    if (i == 0) rowptr[n] = e;
}

// position = atomicAdd on working copy of rowptr -> absolute slot directly
__global__ void k_fill(const int* __restrict__ srcv, const int* __restrict__ dstv,
                       int* rowwork, int* csr_src, int e) {
    int i = blockIdx.x * blockDim.x + threadIdx.x;
    if (i < e) {
        int d = dstv[i];
        int pos = atomicAdd(&rowwork[d], 1);
        csr_src[pos] = srcv[i];
    }
}

// ---------------- GEMM: G = (X @ W^T + b) * dis[row], output fp16 ----------------
// block = 512 threads, tile 128x128, K chunked by 32. Thread: 8 rows x 4 cols.
__global__ __launch_bounds__(512, 4) void k_gemm(const float* __restrict__ X,
                                                 const float* __restrict__ W,
                                                 const float* __restrict__ B,
                                                 const float* __restrict__ dis,
                                                 __half* __restrict__ Gh, int n) {
    __shared__ float Wt[KC][132];   // Wt[k][j] = W[j][kc+k]
    __shared__ float Xt[KC][132];   // Xt[k][r] = X[row0+r][kc+k]
    const int t = threadIdx.x;
    const int row0 = blockIdx.x * 128;
    const int j0 = (t & 31) * 4;
    const int r0 = (t >> 5) * 8;

    const float4* X4 = (const float4*)X;
    const float4* W4 = (const float4*)W;

    float acc[8][4];
    #pragma unroll
    for (int r = 0; r < 8; ++r)
        #pragma unroll
        for (int c = 0; c < 4; ++c) acc[r][c] = 0.f;

    const int srow = t >> 3;        // 0..63
    const int skq  = t & 7;         // 0..7

    #pragma unroll 1
    for (int kc = 0; kc < D; kc += KC) {
        #pragma unroll
        for (int i = 0; i < 2; ++i) {
            int row = srow + i * 64;
            float4 xv = make_float4(0.f, 0.f, 0.f, 0.f);
            int grow = row0 + row;
            if (grow < n) xv = X4[(size_t)grow * 32 + (kc >> 2) + skq];
            Xt[skq * 4 + 0][row] = xv.x;
            Xt[skq * 4 + 1][row] = xv.y;
            Xt[skq * 4 + 2][row] = xv.z;
            Xt[skq * 4 + 3][row] = xv.w;
            float4 wv = W4[(size_t)row * 32 + (kc >> 2) + skq];   // row == output col j
            Wt[skq * 4 + 0][row] = wv.x;
            Wt[skq * 4 + 1][row] = wv.y;
            Wt[skq * 4 + 2][row] = wv.z;
            Wt[skq * 4 + 3][row] = wv.w;
        }
        __syncthreads();

        #pragma unroll 2
        for (int kg = 0; kg < KC; kg += 4) {
            float4 w[4], xa[4], xb[4];
            #pragma unroll
            for (int kk = 0; kk < 4; ++kk) {
                w[kk]  = *(const float4*)&Wt[kg + kk][j0];
                xa[kk] = *(const float4*)&Xt[kg + kk][r0];
                xb[kk] = *(const float4*)&Xt[kg + kk][r0 + 4];
            }
            #pragma unroll
            for (int kk = 0; kk < 4; ++kk) {
                float xr[8] = {xa[kk].x, xa[kk].y, xa[kk].z, xa[kk].w,
                               xb[kk].x, xb[kk].y, xb[kk].z, xb[kk].w};
                #pragma unroll
                for (int r = 0; r < 8; ++r) {
                    acc[r][0] = fmaf(xr[r], w[kk].x, acc[r][0]);
                    acc[r][1] = fmaf(xr[r], w[kk].y, acc[r][1]);
                    acc[r][2] = fmaf(xr[r], w[kk].z, acc[r][2]);
                    acc[r][3] = fmaf(xr[r], w[kk].w, acc[r][3]);
                }
            }
        }
        __syncthreads();
    }

    // ---- epilogue: bias, dis scale, fp16 pack, store ----
    float4 bj = *(const float4*)&B[j0];
    #pragma unroll
    for (int r = 0; r < 8; ++r) {
        int row = row0 + r0 + r;
        if (row < n) {
            float ds = dis[row];
            __half2 ha = __floats2half2_rn((acc[r][0] + bj.x) * ds, (acc[r][1] + bj.y) * ds);
            __half2 hb = __floats2half2_rn((acc[r][2] + bj.z) * ds, (acc[r][3] + bj.w) * ds);
            uint2 u;
            u.x = *(unsigned int*)&ha;
            u.y = *(unsigned int*)&hb;
            *(uint2*)&Gh[(size_t)row * D + j0] = u;
        }
    }
}

// ---------------- gather-aggregate + self loop + PReLU ----------------
// out[i] = prelu( dis[i] * ( G[i] + sum_{src->i} G[src] ) ), G in fp16
// one 64-lane wave per node; lane owns one half2 (2 cols)
__global__ __launch_bounds__(256) void k_gather(const __half* __restrict__ G,
                                                const float* __restrict__ dis,
                                                const int* __restrict__ rowptr,
                                                const int* __restrict__ csr_src,
                                                const float* __restrict__ a,
                                                float* __restrict__ O, int n) {
    int wid = (blockIdx.x * 256 + threadIdx.x) >> 6;
    if (wid >= n) return;
    int lane = threadIdx.x & 63;
    const __half2* Gv = (const __half2*)G;
    float2 s0f = __half22float2(Gv[(size_t)wid * 64 + lane]);   // self contribution
    float accx = s0f.x, accy = s0f.y;
    int e = rowptr[wid], e1 = rowptr[wid + 1];
    for (; e + 4 <= e1; e += 4) {
        int s0 = csr_src[e + 0];
        int s1 = csr_src[e + 1];
        int s2 = csr_src[e + 2];
        int s3 = csr_src[e + 3];
        float2 g0 = __half22float2(Gv[(size_t)s0 * 64 + lane]);
        float2 g1 = __half22float2(Gv[(size_t)s1 * 64 + lane]);
        float2 g2 = __half22float2(Gv[(size_t)s2 * 64 + lane]);
        float2 g3 = __half22float2(Gv[(size_t)s3 * 64 + lane]);
        accx += g0.x + g1.x + g2.x + g3.x;
        accy += g0.y + g1.y + g2.y + g3.y;
    }
    for (; e < e1; ++e) {
        int s = csr_src[e];
        float2 g = __half22float2(Gv[(size_t)s * 64 + lane]);
        accx += g.x;
        accy += g.y;
    }
    float dsc = dis[wid];
    float al = a[0];
    float vx = accx * dsc, vy = accy * dsc;
    vx = vx > 0.f ? vx : al * vx;
    vy = vy > 0.f ? vy : al * vy;
    ((float2*)O)[(size_t)wid * 64 + lane] = make_float2(vx, vy);
}

extern "C" void kernel_launch(void* const* d_in, const int* in_sizes, int n_in,
                              void* d_out, int out_size, void* d_ws, size_t ws_size,
                              hipStream_t stream) {
    const float* x  = (const float*)d_in[0];
    const int*   ei = (const int*)d_in[1];
    const float* W1 = (const float*)d_in[2];
    const float* b1 = (const float*)d_in[3];
    const float* a1 = (const float*)d_in[4];
    const float* W2 = (const float*)d_in[5];
    const float* b2 = (const float*)d_in[6];
    const float* a2 = (const float*)d_in[7];

    const int n = in_sizes[0] / D;
    const int e = in_sizes[1] / 2;
    const int* srcv = ei;
    const int* dstv = ei + e;

    char* ws = (char*)d_ws;
    size_t off = 0;
    auto alloc = [&](size_t bytes) {
        void* p = ws + off;
        off = (off + bytes + 255) & ~(size_t)255;
        return p;
    };
    int*    deg     = (int*)   alloc((size_t)n * 4);
    float*  dis     = (float*) alloc((size_t)n * 4);
    int*    rowptr  = (int*)   alloc((size_t)(n + 1) * 4);
    int*    rowwork = (int*)   alloc((size_t)n * 4);
    int*    bsum    = (int*)   alloc(1024);
    int*    csr_src = (int*)   alloc((size_t)e * 4);
    __half* bufH    = (__half*)alloc((size_t)n * D * 2);
    float*  h1      = (float*)d_out;   // fp32 intermediate lives in d_out (fully overwritten later)
    float*  out     = (float*)d_out;

    dim3 blk(256);
    const int nb = (n + 1023) / 1024;

    hipMemsetAsync(deg, 0, (size_t)n * 4, stream);
    k_count<<<(e + 255) / 256, blk, 0, stream>>>(dstv, deg, e);
    k_dis  <<<(n + 255) / 256, blk, 0, stream>>>(deg, dis, n);
    k_scan1<<<nb, blk, 0, stream>>>(deg, rowptr, bsum, n);
    k_scan2<<<1, blk, 0, stream>>>(bsum, nb);
    k_scan3<<<(n + 255) / 256, blk, 0, stream>>>(rowptr, rowwork, bsum, n, e);
    k_fill <<<(e + 255) / 256, blk, 0, stream>>>(srcv, dstv, rowwork, csr_src, e);

    const int gat_grid = (n * 64 + 255) / 256;   // one wave per node
    const int gemm_grid = (n + 127) / 128;

    // layer 1: x -> G1(bufH, fp16) -> h1(d_out, fp32)
    k_gemm  <<<gemm_grid, 512, 0, stream>>>(x, W1, b1, dis, bufH, n);
    k_gather<<<gat_grid, blk, 0, stream>>>(bufH, dis, rowptr, csr_src, a1, h1, n);
    // layer 2: h1 -> G2(bufH, fp16) -> out
    k_gemm  <<<gemm_grid, 512, 0, stream>>>(h1, W2, b2, dis, bufH, n);
    k_gather<<<gat_grid, blk, 0, stream>>>(bufH, dis, rowptr, csr_src, a2, out, n);
}

// Round 5
// 344.649 us; speedup vs baseline: 16.7603x; 1.3327x over previous
//
#include <hip/hip_runtime.h>
#include <hip/hip_fp16.h>

#define D 128
#define KC 32
#define PCH 16384   // edges per partition block

// ================= bucketed CSR build (counting sort by dst>>8) =================
// bucket = dst >> 8  (256 nodes per bucket)

__global__ __launch_bounds__(256) void k_hist(const int* __restrict__ dstv, int* bcnt,
                                              int e, int nb) {
    __shared__ int h[512];
    for (int i = threadIdx.x; i < nb; i += 256) h[i] = 0;
    __syncthreads();
    int stride = gridDim.x * 256;
    for (int i = blockIdx.x * 256 + threadIdx.x; i < e; i += stride)
        atomicAdd(&h[dstv[i] >> 8], 1);
    __syncthreads();
    for (int i = threadIdx.x; i < nb; i += 256)
        if (h[i]) atomicAdd(&bcnt[i], h[i]);
}

__global__ __launch_bounds__(512) void k_bscan(const int* __restrict__ bcnt, int* bbase,
                                               int* bcur, int nb, int e) {
    __shared__ int sd[512];
    int t = threadIdx.x;
    int v = (t < nb) ? bcnt[t] : 0;
    sd[t] = v;
    __syncthreads();
    for (int off = 1; off < 512; off <<= 1) {
        int x = (t >= off) ? sd[t - off] : 0;
        __syncthreads();
        sd[t] += x;
        __syncthreads();
    }
    int excl = sd[t] - v;
    if (t < nb) { bbase[t] = excl; bcur[t] = excl; }
    if (t == nb - 1) bbase[nb] = e;
}

// partition edges into bucket-contiguous ebuf, packed (src<<8)|(dst&255)
__global__ __launch_bounds__(256) void k_part(const int* __restrict__ srcv,
                                              const int* __restrict__ dstv,
                                              int* bcur, unsigned int* __restrict__ ebuf,
                                              int e, int nb) {
    __shared__ int h[512];
    __shared__ int base[512];
    int c0 = blockIdx.x * PCH;
    int c1 = min(c0 + PCH, e);
    for (int i = threadIdx.x; i < nb; i += 256) h[i] = 0;
    __syncthreads();
    for (int i = c0 + threadIdx.x; i < c1; i += 256)
        atomicAdd(&h[dstv[i] >> 8], 1);
    __syncthreads();
    for (int i = threadIdx.x; i < nb; i += 256) {
        int c = h[i];
        base[i] = c ? atomicAdd(&bcur[i], c) : 0;
    }
    __syncthreads();
    for (int i = threadIdx.x; i < nb; i += 256) h[i] = 0;
    __syncthreads();
    for (int i = c0 + threadIdx.x; i < c1; i += 256) {
        int d = dstv[i];
        int b = d >> 8;
        int pos = atomicAdd(&h[b], 1);
        ebuf[base[b] + pos] = ((unsigned int)srcv[i] << 8) | (unsigned int)(d & 255);
    }
}

// per-bucket: local count -> rowptr + dis, then fill csr_src (contiguous slice)
__global__ __launch_bounds__(256) void k_bucket(const unsigned int* __restrict__ ebuf,
                                                const int* __restrict__ bbase,
                                                int* __restrict__ rowptr,
                                                int* __restrict__ csr_src,
                                                float* __restrict__ dis, int n, int e) {
    __shared__ int cnt[256];
    __shared__ int off[256];
    int b = blockIdx.x;
    int t = threadIdx.x;
    int s0 = bbase[b], s1 = bbase[b + 1];
    cnt[t] = 0;
    __syncthreads();
    for (int i = s0 + t; i < s1; i += 256)
        atomicAdd(&cnt[ebuf[i] & 255], 1);
    __syncthreads();
    int v = cnt[t];
    off[t] = v;
    __syncthreads();
    for (int o = 1; o < 256; o <<= 1) {
        int x = (t >= o) ? off[t - o] : 0;
        __syncthreads();
        off[t] += x;
        __syncthreads();
    }
    int excl = off[t] - v;
    int node = b * 256 + t;
    if (node < n) {
        rowptr[node] = s0 + excl;
        dis[node] = rsqrtf((float)(v + 1));   // +1 self loop
    }
    if (b == 0 && t == 0) rowptr[n] = e;
    __syncthreads();
    cnt[t] = excl;   // reuse as local cursor
    __syncthreads();
    for (int i = s0 + t; i < s1; i += 256) {
        unsigned int u = ebuf[i];
        int pos = atomicAdd(&cnt[u & 255], 1);
        csr_src[s0 + pos] = (int)(u >> 8);
    }
}

// ================= GEMM: G = (X @ W^T + b) * dis[row], output fp16 =================
// block = 512 threads, tile 128x128, K chunked by 32. Thread: 8 rows x 4 cols.
__global__ __launch_bounds__(512, 4) void k_gemm(const float* __restrict__ X,
                                                 const float* __restrict__ W,
                                                 const float* __restrict__ B,
                                                 const float* __restrict__ dis,
                                                 __half* __restrict__ Gh, int n) {
    __shared__ float Wt[KC][132];   // Wt[k][j] = W[j][kc+k]
    __shared__ float Xt[KC][132];   // Xt[k][r] = X[row0+r][kc+k]
    const int t = threadIdx.x;
    const int row0 = blockIdx.x * 128;
    const int j0 = (t & 31) * 4;
    const int r0 = (t >> 5) * 8;

    const float4* X4 = (const float4*)X;
    const float4* W4 = (const float4*)W;

    float acc[8][4];
    #pragma unroll
    for (int r = 0; r < 8; ++r)
        #pragma unroll
        for (int c = 0; c < 4; ++c) acc[r][c] = 0.f;

    const int srow = t >> 3;        // 0..63
    const int skq  = t & 7;         // 0..7

    #pragma unroll 1
    for (int kc = 0; kc < D; kc += KC) {
        #pragma unroll
        for (int i = 0; i < 2; ++i) {
            int row = srow + i * 64;
            float4 xv = make_float4(0.f, 0.f, 0.f, 0.f);
            int grow = row0 + row;
            if (grow < n) xv = X4[(size_t)grow * 32 + (kc >> 2) + skq];
            Xt[skq * 4 + 0][row] = xv.x;
            Xt[skq * 4 + 1][row] = xv.y;
            Xt[skq * 4 + 2][row] = xv.z;
            Xt[skq * 4 + 3][row] = xv.w;
            float4 wv = W4[(size_t)row * 32 + (kc >> 2) + skq];   // row == output col j
            Wt[skq * 4 + 0][row] = wv.x;
            Wt[skq * 4 + 1][row] = wv.y;
            Wt[skq * 4 + 2][row] = wv.z;
            Wt[skq * 4 + 3][row] = wv.w;
        }
        __syncthreads();

        #pragma unroll 2
        for (int kg = 0; kg < KC; kg += 4) {
            float4 w[4], xa[4], xb[4];
            #pragma unroll
            for (int kk = 0; kk < 4; ++kk) {
                w[kk]  = *(const float4*)&Wt[kg + kk][j0];
                xa[kk] = *(const float4*)&Xt[kg + kk][r0];
                xb[kk] = *(const float4*)&Xt[kg + kk][r0 + 4];
            }
            #pragma unroll
            for (int kk = 0; kk < 4; ++kk) {
                float xr[8] = {xa[kk].x, xa[kk].y, xa[kk].z, xa[kk].w,
                               xb[kk].x, xb[kk].y, xb[kk].z, xb[kk].w};
                #pragma unroll
                for (int r = 0; r < 8; ++r) {
                    acc[r][0] = fmaf(xr[r], w[kk].x, acc[r][0]);
                    acc[r][1] = fmaf(xr[r], w[kk].y, acc[r][1]);
                    acc[r][2] = fmaf(xr[r], w[kk].z, acc[r][2]);
                    acc[r][3] = fmaf(xr[r], w[kk].w, acc[r][3]);
                }
            }
        }
        __syncthreads();
    }

    // ---- epilogue: bias, dis scale, fp16 pack, store ----
    float4 bj = *(const float4*)&B[j0];
    #pragma unroll
    for (int r = 0; r < 8; ++r) {
        int row = row0 + r0 + r;
        if (row < n) {
            float ds = dis[row];
            __half2 ha = __floats2half2_rn((acc[r][0] + bj.x) * ds, (acc[r][1] + bj.y) * ds);
            __half2 hb = __floats2half2_rn((acc[r][2] + bj.z) * ds, (acc[r][3] + bj.w) * ds);
            uint2 u;
            u.x = *(unsigned int*)&ha;
            u.y = *(unsigned int*)&hb;
            *(uint2*)&Gh[(size_t)row * D + j0] = u;
        }
    }
}

// ================= gather-aggregate + self loop + PReLU =================
// out[i] = prelu( dis[i] * ( G[i] + sum_{src->i} G[src] ) ), G in fp16
__global__ __launch_bounds__(256) void k_gather(const __half* __restrict__ G,
                                                const float* __restrict__ dis,
                                                const int* __restrict__ rowptr,
                                                const int* __restrict__ csr_src,
                                                const float* __restrict__ a,
                                                float* __restrict__ O, int n) {
    int wid = (blockIdx.x * 256 + threadIdx.x) >> 6;
    if (wid >= n) return;
    int lane = threadIdx.x & 63;
    const __half2* Gv = (const __half2*)G;
    float2 s0f = __half22float2(Gv[(size_t)wid * 64 + lane]);   // self contribution
    float accx = s0f.x, accy = s0f.y;
    int e = rowptr[wid], e1 = rowptr[wid + 1];
    for (; e + 4 <= e1; e += 4) {
        int s0 = csr_src[e + 0];
        int s1 = csr_src[e + 1];
        int s2 = csr_src[e + 2];
        int s3 = csr_src[e + 3];
        float2 g0 = __half22float2(Gv[(size_t)s0 * 64 + lane]);
        float2 g1 = __half22float2(Gv[(size_t)s1 * 64 + lane]);
        float2 g2 = __half22float2(Gv[(size_t)s2 * 64 + lane]);
        float2 g3 = __half22float2(Gv[(size_t)s3 * 64 + lane]);
        accx += g0.x + g1.x + g2.x + g3.x;
        accy += g0.y + g1.y + g2.y + g3.y;
    }
    for (; e < e1; ++e) {
        int s = csr_src[e];
        float2 g = __half22float2(Gv[(size_t)s * 64 + lane]);
        accx += g.x;
        accy += g.y;
    }
    float dsc = dis[wid];
    float al = a[0];
    float vx = accx * dsc, vy = accy * dsc;
    vx = vx > 0.f ? vx : al * vx;
    vy = vy > 0.f ? vy : al * vy;
    ((float2*)O)[(size_t)wid * 64 + lane] = make_float2(vx, vy);
}

extern "C" void kernel_launch(void* const* d_in, const int* in_sizes, int n_in,
                              void* d_out, int out_size, void* d_ws, size_t ws_size,
                              hipStream_t stream) {
    const float* x  = (const float*)d_in[0];
    const int*   ei = (const int*)d_in[1];
    const float* W1 = (const float*)d_in[2];
    const float* b1 = (const float*)d_in[3];
    const float* a1 = (const float*)d_in[4];
    const float* W2 = (const float*)d_in[5];
    const float* b2 = (const float*)d_in[6];
    const float* a2 = (const float*)d_in[7];

    const int n = in_sizes[0] / D;
    const int e = in_sizes[1] / 2;
    const int* srcv = ei;
    const int* dstv = ei + e;
    const int nb = (n + 255) >> 8;   // buckets of 256 nodes (requires nb <= 512, n < 2^24)

    char* ws = (char*)d_ws;
    size_t off = 0;
    auto alloc = [&](size_t bytes) {
        void* p = ws + off;
        off = (off + bytes + 255) & ~(size_t)255;
        return p;
    };
    float*        dis     = (float*)       alloc((size_t)n * 4);
    int*          rowptr  = (int*)         alloc((size_t)(n + 1) * 4);
    int*          csr_src = (int*)         alloc((size_t)e * 4);
    int*          bcnt    = (int*)         alloc(512 * 4);
    int*          bbase   = (int*)         alloc(513 * 4);
    int*          bcur    = (int*)         alloc(512 * 4);
    unsigned int* ebuf    = (unsigned int*)alloc((size_t)e * 4);
    __half*       bufH    = (__half*)      alloc((size_t)n * D * 2);
    float*        h1      = (float*)d_out;   // fp32 intermediate (fully overwritten later)
    float*        out     = (float*)d_out;

    dim3 blk(256);
    const int npart = (e + PCH - 1) / PCH;

    hipMemsetAsync(bcnt, 0, 512 * 4, stream);
    k_hist  <<<256, blk, 0, stream>>>(dstv, bcnt, e, nb);
    k_bscan <<<1, 512, 0, stream>>>(bcnt, bbase, bcur, nb, e);
    k_part  <<<npart, blk, 0, stream>>>(srcv, dstv, bcur, ebuf, e, nb);
    k_bucket<<<nb, blk, 0, stream>>>(ebuf, bbase, rowptr, csr_src, dis, n, e);

    const int gat_grid = (n * 64 + 255) / 256;   // one wave per node
    const int gemm_grid = (n + 127) / 128;

    // layer 1: x -> G1(bufH, fp16) -> h1(d_out, fp32)
    k_gemm  <<<gemm_grid, 512, 0, stream>>>(x, W1, b1, dis, bufH, n);
    k_gather<<<gat_grid, blk, 0, stream>>>(bufH, dis, rowptr, csr_src, a1, h1, n);
    // layer 2: h1 -> G2(bufH, fp16) -> out
    k_gemm  <<<gemm_grid, 512, 0, stream>>>(h1, W2, b2, dis, bufH, n);
    k_gather<<<gat_grid, blk, 0, stream>>>(bufH, dis, rowptr, csr_src, a2, out, n);
}

// Round 6
// 326.471 us; speedup vs baseline: 17.6935x; 1.0557x over previous
//
#include <hip/hip_runtime.h>
#include <hip/hip_fp16.h>

#define D 128
#define KC 32
#define PCH 16384   // edges per partition block

// ================= bucketed CSR build (counting sort by dst>>8) =================
// bucket = dst >> 8  (256 nodes per bucket)

__global__ __launch_bounds__(256) void k_hist(const int* __restrict__ dstv, int* bcnt,
                                              int e, int nb) {
    __shared__ int h[512];
    for (int i = threadIdx.x; i < nb; i += 256) h[i] = 0;
    __syncthreads();
    int stride = gridDim.x * 256;
    for (int i = blockIdx.x * 256 + threadIdx.x; i < e; i += stride)
        atomicAdd(&h[dstv[i] >> 8], 1);
    __syncthreads();
    for (int i = threadIdx.x; i < nb; i += 256)
        if (h[i]) atomicAdd(&bcnt[i], h[i]);
}

__global__ __launch_bounds__(512) void k_bscan(const int* __restrict__ bcnt, int* bbase,
                                               int* bcur, int nb, int e) {
    __shared__ int sd[512];
    int t = threadIdx.x;
    int v = (t < nb) ? bcnt[t] : 0;
    sd[t] = v;
    __syncthreads();
    for (int off = 1; off < 512; off <<= 1) {
        int x = (t >= off) ? sd[t - off] : 0;
        __syncthreads();
        sd[t] += x;
        __syncthreads();
    }
    int excl = sd[t] - v;
    if (t < nb) { bbase[t] = excl; bcur[t] = excl; }
    if (t == nb - 1) bbase[nb] = e;
}

// partition edges into bucket-contiguous ebuf, packed (src<<8)|(dst&255)
__global__ __launch_bounds__(256) void k_part(const int* __restrict__ srcv,
                                              const int* __restrict__ dstv,
                                              int* bcur, unsigned int* __restrict__ ebuf,
                                              int e, int nb) {
    __shared__ int h[512];
    __shared__ int base[512];
    int c0 = blockIdx.x * PCH;
    int c1 = min(c0 + PCH, e);
    for (int i = threadIdx.x; i < nb; i += 256) h[i] = 0;
    __syncthreads();
    for (int i = c0 + threadIdx.x; i < c1; i += 256)
        atomicAdd(&h[dstv[i] >> 8], 1);
    __syncthreads();
    for (int i = threadIdx.x; i < nb; i += 256) {
        int c = h[i];
        base[i] = c ? atomicAdd(&bcur[i], c) : 0;
    }
    __syncthreads();
    for (int i = threadIdx.x; i < nb; i += 256) h[i] = 0;
    __syncthreads();
    for (int i = c0 + threadIdx.x; i < c1; i += 256) {
        int d = dstv[i];
        int b = d >> 8;
        int pos = atomicAdd(&h[b], 1);
        ebuf[base[b] + pos] = ((unsigned int)srcv[i] << 8) | (unsigned int)(d & 255);
    }
}

// per-bucket: local count -> rowptr + dis, then fill csr_src (contiguous slice)
__global__ __launch_bounds__(256) void k_bucket(const unsigned int* __restrict__ ebuf,
                                                const int* __restrict__ bbase,
                                                int* __restrict__ rowptr,
                                                int* __restrict__ csr_src,
                                                float* __restrict__ dis, int n, int e) {
    __shared__ int cnt[256];
    __shared__ int off[256];
    int b = blockIdx.x;
    int t = threadIdx.x;
    int s0 = bbase[b], s1 = bbase[b + 1];
    cnt[t] = 0;
    __syncthreads();
    for (int i = s0 + t; i < s1; i += 256)
        atomicAdd(&cnt[ebuf[i] & 255], 1);
    __syncthreads();
    int v = cnt[t];
    off[t] = v;
    __syncthreads();
    for (int o = 1; o < 256; o <<= 1) {
        int x = (t >= o) ? off[t - o] : 0;
        __syncthreads();
        off[t] += x;
        __syncthreads();
    }
    int excl = off[t] - v;
    int node = b * 256 + t;
    if (node < n) {
        rowptr[node] = s0 + excl;
        dis[node] = rsqrtf((float)(v + 1));   // +1 self loop
    }
    if (b == 0 && t == 0) rowptr[n] = e;
    __syncthreads();
    cnt[t] = excl;   // reuse as local cursor
    __syncthreads();
    for (int i = s0 + t; i < s1; i += 256) {
        unsigned int u = ebuf[i];
        int pos = atomicAdd(&cnt[u & 255], 1);
        csr_src[s0 + pos] = (int)(u >> 8);
    }
}

// ================= GEMM: G = (X @ W^T + b) * dis[row], output fp16 =================
// block = 512 threads, tile 128x128, K chunked by 32. Thread: 8 rows x 4 cols.
__global__ __launch_bounds__(512, 4) void k_gemm(const float* __restrict__ X,
                                                 const float* __restrict__ W,
                                                 const float* __restrict__ B,
                                                 const float* __restrict__ dis,
                                                 __half* __restrict__ Gh, int n) {
    __shared__ float Wt[KC][132];   // Wt[k][j] = W[j][kc+k]
    __shared__ float Xt[KC][132];   // Xt[k][r] = X[row0+r][kc+k]
    const int t = threadIdx.x;
    const int row0 = blockIdx.x * 128;
    const int j0 = (t & 31) * 4;
    const int r0 = (t >> 5) * 8;

    const float4* X4 = (const float4*)X;
    const float4* W4 = (const float4*)W;

    float acc[8][4];
    #pragma unroll
    for (int r = 0; r < 8; ++r)
        #pragma unroll
        for (int c = 0; c < 4; ++c) acc[r][c] = 0.f;

    const int srow = t >> 3;        // 0..63
    const int skq  = t & 7;         // 0..7

    #pragma unroll 1
    for (int kc = 0; kc < D; kc += KC) {
        #pragma unroll
        for (int i = 0; i < 2; ++i) {
            int row = srow + i * 64;
            float4 xv = make_float4(0.f, 0.f, 0.f, 0.f);
            int grow = row0 + row;
            if (grow < n) xv = X4[(size_t)grow * 32 + (kc >> 2) + skq];
            Xt[skq * 4 + 0][row] = xv.x;
            Xt[skq * 4 + 1][row] = xv.y;
            Xt[skq * 4 + 2][row] = xv.z;
            Xt[skq * 4 + 3][row] = xv.w;
            float4 wv = W4[(size_t)row * 32 + (kc >> 2) + skq];   // row == output col j
            Wt[skq * 4 + 0][row] = wv.x;
            Wt[skq * 4 + 1][row] = wv.y;
            Wt[skq * 4 + 2][row] = wv.z;
            Wt[skq * 4 + 3][row] = wv.w;
        }
        __syncthreads();

        #pragma unroll 2
        for (int kg = 0; kg < KC; kg += 4) {
            float4 w[4], xa[4], xb[4];
            #pragma unroll
            for (int kk = 0; kk < 4; ++kk) {
                w[kk]  = *(const float4*)&Wt[kg + kk][j0];
                xa[kk] = *(const float4*)&Xt[kg + kk][r0];
                xb[kk] = *(const float4*)&Xt[kg + kk][r0 + 4];
            }
            #pragma unroll
            for (int kk = 0; kk < 4; ++kk) {
                float xr[8] = {xa[kk].x, xa[kk].y, xa[kk].z, xa[kk].w,
                               xb[kk].x, xb[kk].y, xb[kk].z, xb[kk].w};
                #pragma unroll
                for (int r = 0; r < 8; ++r) {
                    acc[r][0] = fmaf(xr[r], w[kk].x, acc[r][0]);
                    acc[r][1] = fmaf(xr[r], w[kk].y, acc[r][1]);
                    acc[r][2] = fmaf(xr[r], w[kk].z, acc[r][2]);
                    acc[r][3] = fmaf(xr[r], w[kk].w, acc[r][3]);
                }
            }
        }
        __syncthreads();
    }

    // ---- epilogue: bias, dis scale, fp16 pack, store ----
    float4 bj = *(const float4*)&B[j0];
    #pragma unroll
    for (int r = 0; r < 8; ++r) {
        int row = row0 + r0 + r;
        if (row < n) {
            float ds = dis[row];
            __half2 ha = __floats2half2_rn((acc[r][0] + bj.x) * ds, (acc[r][1] + bj.y) * ds);
            __half2 hb = __floats2half2_rn((acc[r][2] + bj.z) * ds, (acc[r][3] + bj.w) * ds);
            uint2 u;
            u.x = *(unsigned int*)&ha;
            u.y = *(unsigned int*)&hb;
            *(uint2*)&Gh[(size_t)row * D + j0] = u;
        }
    }
}

// ================= gather-aggregate + self loop + PReLU =================
// out[i] = prelu( dis[i] * ( G[i] + sum_{src->i} G[src] ) ), G in fp16
// TWO nodes per wave: lanes 0-31 -> node 2*pair, lanes 32-63 -> node 2*pair+1.
// Each lane owns 4 columns (uint2 = 4 halves, 8 B) -> one load instruction
// fetches two different src rows; unroll 4 -> 8 rows in flight per wave.
__global__ __launch_bounds__(256) void k_gather(const __half* __restrict__ G,
                                                const float* __restrict__ dis,
                                                const int* __restrict__ rowptr,
                                                const int* __restrict__ csr_src,
                                                const float* __restrict__ a,
                                                float* __restrict__ O, int n, int npair) {
    int pair = (blockIdx.x * 256 + threadIdx.x) >> 6;
    if (pair >= npair) return;
    int lane = threadIdx.x & 63;
    int half = lane >> 5;
    int cl   = lane & 31;          // column quad 0..31
    int node = pair * 2 + half;
    if (node >= n) node = n - 1;   // duplicate last node (writes identical data)

    const uint2* Gv = (const uint2*)G;   // one uint2 = 4 halves
    uint2 su = Gv[(size_t)node * 32 + cl];
    float2 f0 = __half22float2(*(__half2*)&su.x);
    float2 f1 = __half22float2(*(__half2*)&su.y);
    float ax = f0.x, ay = f0.y, az = f1.x, aw = f1.y;

    int e = rowptr[node], e1 = rowptr[node + 1];
    for (; e + 4 <= e1; e += 4) {
        int s0 = csr_src[e + 0];
        int s1 = csr_src[e + 1];
        int s2 = csr_src[e + 2];
        int s3 = csr_src[e + 3];
        uint2 u0 = Gv[(size_t)s0 * 32 + cl];
        uint2 u1 = Gv[(size_t)s1 * 32 + cl];
        uint2 u2 = Gv[(size_t)s2 * 32 + cl];
        uint2 u3 = Gv[(size_t)s3 * 32 + cl];
        float2 a0 = __half22float2(*(__half2*)&u0.x), b0 = __half22float2(*(__half2*)&u0.y);
        float2 a1f = __half22float2(*(__half2*)&u1.x), b1f = __half22float2(*(__half2*)&u1.y);
        float2 a2f = __half22float2(*(__half2*)&u2.x), b2f = __half22float2(*(__half2*)&u2.y);
        float2 a3f = __half22float2(*(__half2*)&u3.x), b3f = __half22float2(*(__half2*)&u3.y);
        ax += a0.x + a1f.x + a2f.x + a3f.x;
        ay += a0.y + a1f.y + a2f.y + a3f.y;
        az += b0.x + b1f.x + b2f.x + b3f.x;
        aw += b0.y + b1f.y + b2f.y + b3f.y;
    }
    for (; e < e1; ++e) {
        int s = csr_src[e];
        uint2 u = Gv[(size_t)s * 32 + cl];
        float2 ga = __half22float2(*(__half2*)&u.x);
        float2 gb = __half22float2(*(__half2*)&u.y);
        ax += ga.x; ay += ga.y; az += gb.x; aw += gb.y;
    }

    float dsc = dis[node];
    float al = a[0];
    float vx = ax * dsc, vy = ay * dsc, vz = az * dsc, vw = aw * dsc;
    vx = vx > 0.f ? vx : al * vx;
    vy = vy > 0.f ? vy : al * vy;
    vz = vz > 0.f ? vz : al * vz;
    vw = vw > 0.f ? vw : al * vw;
    ((float4*)O)[(size_t)node * 32 + cl] = make_float4(vx, vy, vz, vw);
}

extern "C" void kernel_launch(void* const* d_in, const int* in_sizes, int n_in,
                              void* d_out, int out_size, void* d_ws, size_t ws_size,
                              hipStream_t stream) {
    const float* x  = (const float*)d_in[0];
    const int*   ei = (const int*)d_in[1];
    const float* W1 = (const float*)d_in[2];
    const float* b1 = (const float*)d_in[3];
    const float* a1 = (const float*)d_in[4];
    const float* W2 = (const float*)d_in[5];
    const float* b2 = (const float*)d_in[6];
    const float* a2 = (const float*)d_in[7];

    const int n = in_sizes[0] / D;
    const int e = in_sizes[1] / 2;
    const int* srcv = ei;
    const int* dstv = ei + e;
    const int nb = (n + 255) >> 8;   // buckets of 256 nodes (requires nb <= 512, n < 2^24)

    char* ws = (char*)d_ws;
    size_t off = 0;
    auto alloc = [&](size_t bytes) {
        void* p = ws + off;
        off = (off + bytes + 255) & ~(size_t)255;
        return p;
    };
    float*        dis     = (float*)       alloc((size_t)n * 4);
    int*          rowptr  = (int*)         alloc((size_t)(n + 1) * 4);
    int*          csr_src = (int*)         alloc((size_t)e * 4);
    int*          bcnt    = (int*)         alloc(512 * 4);
    int*          bbase   = (int*)         alloc(513 * 4);
    int*          bcur    = (int*)         alloc(512 * 4);
    unsigned int* ebuf    = (unsigned int*)alloc((size_t)e * 4);
    __half*       bufH    = (__half*)      alloc((size_t)n * D * 2);
    float*        h1      = (float*)d_out;   // fp32 intermediate (fully overwritten later)
    float*        out     = (float*)d_out;

    dim3 blk(256);
    const int npart = (e + PCH - 1) / PCH;

    hipMemsetAsync(bcnt, 0, 512 * 4, stream);
    k_hist  <<<256, blk, 0, stream>>>(dstv, bcnt, e, nb);
    k_bscan <<<1, 512, 0, stream>>>(bcnt, bbase, bcur, nb, e);
    k_part  <<<npart, blk, 0, stream>>>(srcv, dstv, bcur, ebuf, e, nb);
    k_bucket<<<nb, blk, 0, stream>>>(ebuf, bbase, rowptr, csr_src, dis, n, e);

    const int npair = (n + 1) / 2;
    const int gat_grid = (npair * 64 + 255) / 256;   // one wave per node pair
    const int gemm_grid = (n + 127) / 128;

    // layer 1: x -> G1(bufH, fp16) -> h1(d_out, fp32)
    k_gemm  <<<gemm_grid, 512, 0, stream>>>(x, W1, b1, dis, bufH, n);
    k_gather<<<gat_grid, blk, 0, stream>>>(bufH, dis, rowptr, csr_src, a1, h1, n, npair);
    // layer 2: h1 -> G2(bufH, fp16) -> out
    k_gemm  <<<gemm_grid, 512, 0, stream>>>(h1, W2, b2, dis, bufH, n);
    k_gather<<<gat_grid, blk, 0, stream>>>(bufH, dis, rowptr, csr_src, a2, out, n, npair);
}

// Round 7
// 313.142 us; speedup vs baseline: 18.4466x; 1.0426x over previous
//
#include <hip/hip_runtime.h>
#include <hip/hip_fp16.h>

#define D 128
#define KC 32
#define PCH 2048   // edges per partition block (small -> enough blocks to fill 256 CUs)

// ================= bucketed CSR build (counting sort by dst>>8) =================
// bucket = dst >> 8  (256 nodes per bucket)

__global__ __launch_bounds__(256) void k_hist(const int* __restrict__ dstv, int* bcnt,
                                              int e, int nb) {
    __shared__ int h[512];
    for (int i = threadIdx.x; i < nb; i += 256) h[i] = 0;
    __syncthreads();
    int stride = gridDim.x * 256;
    for (int i = blockIdx.x * 256 + threadIdx.x; i < e; i += stride)
        atomicAdd(&h[dstv[i] >> 8], 1);
    __syncthreads();
    for (int i = threadIdx.x; i < nb; i += 256)
        if (h[i]) atomicAdd(&bcnt[i], h[i]);
}

__global__ __launch_bounds__(512) void k_bscan(const int* __restrict__ bcnt, int* bbase,
                                               int* bcur, int nb, int e) {
    __shared__ int sd[512];
    int t = threadIdx.x;
    int v = (t < nb) ? bcnt[t] : 0;
    sd[t] = v;
    __syncthreads();
    for (int off = 1; off < 512; off <<= 1) {
        int x = (t >= off) ? sd[t - off] : 0;
        __syncthreads();
        sd[t] += x;
        __syncthreads();
    }
    int excl = sd[t] - v;
    if (t < nb) { bbase[t] = excl; bcur[t] = excl; }
    if (t == nb - 1) bbase[nb] = e;
}

// partition edges into bucket-contiguous ebuf, packed (src<<8)|(dst&255)
__global__ __launch_bounds__(256) void k_part(const int* __restrict__ srcv,
                                              const int* __restrict__ dstv,
                                              int* bcur, unsigned int* __restrict__ ebuf,
                                              int e, int nb) {
    __shared__ int h[512];
    __shared__ int base[512];
    int c0 = blockIdx.x * PCH;
    int c1 = min(c0 + PCH, e);
    for (int i = threadIdx.x; i < nb; i += 256) h[i] = 0;
    __syncthreads();
    for (int i = c0 + threadIdx.x; i < c1; i += 256)
        atomicAdd(&h[dstv[i] >> 8], 1);
    __syncthreads();
    for (int i = threadIdx.x; i < nb; i += 256) {
        int c = h[i];
        base[i] = c ? atomicAdd(&bcur[i], c) : 0;
    }
    __syncthreads();
    for (int i = threadIdx.x; i < nb; i += 256) h[i] = 0;
    __syncthreads();
    for (int i = c0 + threadIdx.x; i < c1; i += 256) {
        int d = dstv[i];
        int b = d >> 8;
        int pos = atomicAdd(&h[b], 1);
        ebuf[base[b] + pos] = ((unsigned int)srcv[i] << 8) | (unsigned int)(d & 255);
    }
}

// per-bucket: local count -> rowptr + dis, then fill csr_src (contiguous slice)
__global__ __launch_bounds__(256) void k_bucket(const unsigned int* __restrict__ ebuf,
                                                const int* __restrict__ bbase,
                                                int* __restrict__ rowptr,
                                                int* __restrict__ csr_src,
                                                float* __restrict__ dis, int n, int e) {
    __shared__ int cnt[256];
    __shared__ int off[256];
    int b = blockIdx.x;
    int t = threadIdx.x;
    int s0 = bbase[b], s1 = bbase[b + 1];
    cnt[t] = 0;
    __syncthreads();
    for (int i = s0 + t; i < s1; i += 256)
        atomicAdd(&cnt[ebuf[i] & 255], 1);
    __syncthreads();
    int v = cnt[t];
    off[t] = v;
    __syncthreads();
    for (int o = 1; o < 256; o <<= 1) {
        int x = (t >= o) ? off[t - o] : 0;
        __syncthreads();
        off[t] += x;
        __syncthreads();
    }
    int excl = off[t] - v;
    int node = b * 256 + t;
    if (node < n) {
        rowptr[node] = s0 + excl;
        dis[node] = rsqrtf((float)(v + 1));   // +1 self loop
    }
    if (b == 0 && t == 0) rowptr[n] = e;
    __syncthreads();
    cnt[t] = excl;   // reuse as local cursor
    __syncthreads();
    for (int i = s0 + t; i < s1; i += 256) {
        unsigned int u = ebuf[i];
        int pos = atomicAdd(&cnt[u & 255], 1);
        csr_src[s0 + pos] = (int)(u >> 8);
    }
}

// ================= GEMM: G = (X @ W^T + b) * dis[row], output fp16 =================
// block = 512 threads, tile 128x128, K chunked by 32. Thread: 8 rows x 4 cols.
__global__ __launch_bounds__(512, 4) void k_gemm(const float* __restrict__ X,
                                                 const float* __restrict__ W,
                                                 const float* __restrict__ B,
                                                 const float* __restrict__ dis,
                                                 __half* __restrict__ Gh, int n) {
    __shared__ float Wt[KC][132];   // Wt[k][j] = W[j][kc+k]
    __shared__ float Xt[KC][132];   // Xt[k][r] = X[row0+r][kc+k]
    const int t = threadIdx.x;
    const int row0 = blockIdx.x * 128;
    const int j0 = (t & 31) * 4;
    const int r0 = (t >> 5) * 8;

    const float4* X4 = (const float4*)X;
    const float4* W4 = (const float4*)W;

    float acc[8][4];
    #pragma unroll
    for (int r = 0; r < 8; ++r)
        #pragma unroll
        for (int c = 0; c < 4; ++c) acc[r][c] = 0.f;

    const int srow = t >> 3;        // 0..63
    const int skq  = t & 7;         // 0..7

    #pragma unroll 1
    for (int kc = 0; kc < D; kc += KC) {
        #pragma unroll
        for (int i = 0; i < 2; ++i) {
            int row = srow + i * 64;
            float4 xv = make_float4(0.f, 0.f, 0.f, 0.f);
            int grow = row0 + row;
            if (grow < n) xv = X4[(size_t)grow * 32 + (kc >> 2) + skq];
            Xt[skq * 4 + 0][row] = xv.x;
            Xt[skq * 4 + 1][row] = xv.y;
            Xt[skq * 4 + 2][row] = xv.z;
            Xt[skq * 4 + 3][row] = xv.w;
            float4 wv = W4[(size_t)row * 32 + (kc >> 2) + skq];   // row == output col j
            Wt[skq * 4 + 0][row] = wv.x;
            Wt[skq * 4 + 1][row] = wv.y;
            Wt[skq * 4 + 2][row] = wv.z;
            Wt[skq * 4 + 3][row] = wv.w;
        }
        __syncthreads();

        #pragma unroll 2
        for (int kg = 0; kg < KC; kg += 4) {
            float4 w[4], xa[4], xb[4];
            #pragma unroll
            for (int kk = 0; kk < 4; ++kk) {
                w[kk]  = *(const float4*)&Wt[kg + kk][j0];
                xa[kk] = *(const float4*)&Xt[kg + kk][r0];
                xb[kk] = *(const float4*)&Xt[kg + kk][r0 + 4];
            }
            #pragma unroll
            for (int kk = 0; kk < 4; ++kk) {
                float xr[8] = {xa[kk].x, xa[kk].y, xa[kk].z, xa[kk].w,
                               xb[kk].x, xb[kk].y, xb[kk].z, xb[kk].w};
                #pragma unroll
                for (int r = 0; r < 8; ++r) {
                    acc[r][0] = fmaf(xr[r], w[kk].x, acc[r][0]);
                    acc[r][1] = fmaf(xr[r], w[kk].y, acc[r][1]);
                    acc[r][2] = fmaf(xr[r], w[kk].z, acc[r][2]);
                    acc[r][3] = fmaf(xr[r], w[kk].w, acc[r][3]);
                }
            }
        }
        __syncthreads();
    }

    // ---- epilogue: bias, dis scale, fp16 pack, store ----
    float4 bj = *(const float4*)&B[j0];
    #pragma unroll
    for (int r = 0; r < 8; ++r) {
        int row = row0 + r0 + r;
        if (row < n) {
            float ds = dis[row];
            __half2 ha = __floats2half2_rn((acc[r][0] + bj.x) * ds, (acc[r][1] + bj.y) * ds);
            __half2 hb = __floats2half2_rn((acc[r][2] + bj.z) * ds, (acc[r][3] + bj.w) * ds);
            uint2 u;
            u.x = *(unsigned int*)&ha;
            u.y = *(unsigned int*)&hb;
            *(uint2*)&Gh[(size_t)row * D + j0] = u;
        }
    }
}

// ================= gather-aggregate + self loop + PReLU =================
// out[i] = prelu( dis[i] * ( G[i] + sum_{src->i} G[src] ) ), G in fp16
// TWO nodes per wave: lanes 0-31 -> node 2*pair, lanes 32-63 -> node 2*pair+1.
__global__ __launch_bounds__(256) void k_gather(const __half* __restrict__ G,
                                                const float* __restrict__ dis,
                                                const int* __restrict__ rowptr,
                                                const int* __restrict__ csr_src,
                                                const float* __restrict__ a,
                                                float* __restrict__ O, int n, int npair) {
    int pair = (blockIdx.x * 256 + threadIdx.x) >> 6;
    if (pair >= npair) return;
    int lane = threadIdx.x & 63;
    int half = lane >> 5;
    int cl   = lane & 31;          // column quad 0..31
    int node = pair * 2 + half;
    if (node >= n) node = n - 1;   // duplicate last node (writes identical data)

    const uint2* Gv = (const uint2*)G;   // one uint2 = 4 halves
    uint2 su = Gv[(size_t)node * 32 + cl];
    float2 f0 = __half22float2(*(__half2*)&su.x);
    float2 f1 = __half22float2(*(__half2*)&su.y);
    float ax = f0.x, ay = f0.y, az = f1.x, aw = f1.y;

    int e = rowptr[node], e1 = rowptr[node + 1];
    for (; e + 4 <= e1; e += 4) {
        int s0 = csr_src[e + 0];
        int s1 = csr_src[e + 1];
        int s2 = csr_src[e + 2];
        int s3 = csr_src[e + 3];
        uint2 u0 = Gv[(size_t)s0 * 32 + cl];
        uint2 u1 = Gv[(size_t)s1 * 32 + cl];
        uint2 u2 = Gv[(size_t)s2 * 32 + cl];
        uint2 u3 = Gv[(size_t)s3 * 32 + cl];
        float2 a0 = __half22float2(*(__half2*)&u0.x), b0 = __half22float2(*(__half2*)&u0.y);
        float2 a1f = __half22float2(*(__half2*)&u1.x), b1f = __half22float2(*(__half2*)&u1.y);
        float2 a2f = __half22float2(*(__half2*)&u2.x), b2f = __half22float2(*(__half2*)&u2.y);
        float2 a3f = __half22float2(*(__half2*)&u3.x), b3f = __half22float2(*(__half2*)&u3.y);
        ax += a0.x + a1f.x + a2f.x + a3f.x;
        ay += a0.y + a1f.y + a2f.y + a3f.y;
        az += b0.x + b1f.x + b2f.x + b3f.x;
        aw += b0.y + b1f.y + b2f.y + b3f.y;
    }
    for (; e < e1; ++e) {
        int s = csr_src[e];
        uint2 u = Gv[(size_t)s * 32 + cl];
        float2 ga = __half22float2(*(__half2*)&u.x);
        float2 gb = __half22float2(*(__half2*)&u.y);
        ax += ga.x; ay += ga.y; az += gb.x; aw += gb.y;
    }

    float dsc = dis[node];
    float al = a[0];
    float vx = ax * dsc, vy = ay * dsc, vz = az * dsc, vw = aw * dsc;
    vx = vx > 0.f ? vx : al * vx;
    vy = vy > 0.f ? vy : al * vy;
    vz = vz > 0.f ? vz : al * vz;
    vw = vw > 0.f ? vw : al * vw;
    ((float4*)O)[(size_t)node * 32 + cl] = make_float4(vx, vy, vz, vw);
}

extern "C" void kernel_launch(void* const* d_in, const int* in_sizes, int n_in,
                              void* d_out, int out_size, void* d_ws, size_t ws_size,
                              hipStream_t stream) {
    const float* x  = (const float*)d_in[0];
    const int*   ei = (const int*)d_in[1];
    const float* W1 = (const float*)d_in[2];
    const float* b1 = (const float*)d_in[3];
    const float* a1 = (const float*)d_in[4];
    const float* W2 = (const float*)d_in[5];
    const float* b2 = (const float*)d_in[6];
    const float* a2 = (const float*)d_in[7];

    const int n = in_sizes[0] / D;
    const int e = in_sizes[1] / 2;
    const int* srcv = ei;
    const int* dstv = ei + e;
    const int nb = (n + 255) >> 8;   // buckets of 256 nodes (requires nb <= 512, n < 2^24)

    char* ws = (char*)d_ws;
    size_t off = 0;
    auto alloc = [&](size_t bytes) {
        void* p = ws + off;
        off = (off + bytes + 255) & ~(size_t)255;
        return p;
    };
    float*        dis     = (float*)       alloc((size_t)n * 4);
    int*          rowptr  = (int*)         alloc((size_t)(n + 1) * 4);
    int*          csr_src = (int*)         alloc((size_t)e * 4);
    int*          bcnt    = (int*)         alloc(512 * 4);
    int*          bbase   = (int*)         alloc(513 * 4);
    int*          bcur    = (int*)         alloc(512 * 4);
    unsigned int* ebuf    = (unsigned int*)alloc((size_t)e * 4);
    __half*       bufH    = (__half*)      alloc((size_t)n * D * 2);
    float*        h1      = (float*)d_out;   // fp32 intermediate (fully overwritten later)
    float*        out     = (float*)d_out;

    dim3 blk(256);
    const int npart = (e + PCH - 1) / PCH;

    hipMemsetAsync(bcnt, 0, 512 * 4, stream);
    k_hist  <<<512, blk, 0, stream>>>(dstv, bcnt, e, nb);
    k_bscan <<<1, 512, 0, stream>>>(bcnt, bbase, bcur, nb, e);
    k_part  <<<npart, blk, 0, stream>>>(srcv, dstv, bcur, ebuf, e, nb);
    k_bucket<<<nb, blk, 0, stream>>>(ebuf, bbase, rowptr, csr_src, dis, n, e);

    const int npair = (n + 1) / 2;
    const int gat_grid = (npair * 64 + 255) / 256;   // one wave per node pair
    const int gemm_grid = (n + 127) / 128;

    // layer 1: x -> G1(bufH, fp16) -> h1(d_out, fp32)
    k_gemm  <<<gemm_grid, 512, 0, stream>>>(x, W1, b1, dis, bufH, n);
    k_gather<<<gat_grid, blk, 0, stream>>>(bufH, dis, rowptr, csr_src, a1, h1, n, npair);
    // layer 2: h1 -> G2(bufH, fp16) -> out
    k_gemm  <<<gemm_grid, 512, 0, stream>>>(h1, W2, b2, dis, bufH, n);
    k_gather<<<gat_grid, blk, 0, stream>>>(bufH, dis, rowptr, csr_src, a2, out, n, npair);
}

// Round 8
// 261.290 us; speedup vs baseline: 22.1073x; 1.1984x over previous
//
#include <hip/hip_runtime.h>
#include <hip/hip_fp16.h>

#define D 128
#define KC 32
#define PCH 2048   // edges per partition block

typedef _Float16 half_t;
typedef _Float16 f16x8 __attribute__((ext_vector_type(8)));
typedef _Float16 f16x4 __attribute__((ext_vector_type(4)));
typedef float    f32x4 __attribute__((ext_vector_type(4)));

// ================= bucketed CSR build (counting sort by dst>>8) =================

__global__ __launch_bounds__(256) void k_hist(const int* __restrict__ dstv, int* bcnt,
                                              int e, int nb) {
    __shared__ int h[512];
    for (int i = threadIdx.x; i < nb; i += 256) h[i] = 0;
    __syncthreads();
    int stride = gridDim.x * 256;
    for (int i = blockIdx.x * 256 + threadIdx.x; i < e; i += stride)
        atomicAdd(&h[dstv[i] >> 8], 1);
    __syncthreads();
    for (int i = threadIdx.x; i < nb; i += 256)
        if (h[i]) atomicAdd(&bcnt[i], h[i]);
}

__global__ __launch_bounds__(512) void k_bscan(const int* __restrict__ bcnt, int* bbase,
                                               int* bcur, int nb, int e) {
    __shared__ int sd[512];
    int t = threadIdx.x;
    int v = (t < nb) ? bcnt[t] : 0;
    sd[t] = v;
    __syncthreads();
    for (int off = 1; off < 512; off <<= 1) {
        int x = (t >= off) ? sd[t - off] : 0;
        __syncthreads();
        sd[t] += x;
        __syncthreads();
    }
    int excl = sd[t] - v;
    if (t < nb) { bbase[t] = excl; bcur[t] = excl; }
    if (t == nb - 1) bbase[nb] = e;
}

__global__ __launch_bounds__(256) void k_part(const int* __restrict__ srcv,
                                              const int* __restrict__ dstv,
                                              int* bcur, unsigned int* __restrict__ ebuf,
                                              int e, int nb) {
    __shared__ int h[512];
    __shared__ int base[512];
    int c0 = blockIdx.x * PCH;
    int c1 = min(c0 + PCH, e);
    for (int i = threadIdx.x; i < nb; i += 256) h[i] = 0;
    __syncthreads();
    for (int i = c0 + threadIdx.x; i < c1; i += 256)
        atomicAdd(&h[dstv[i] >> 8], 1);
    __syncthreads();
    for (int i = threadIdx.x; i < nb; i += 256) {
        int c = h[i];
        base[i] = c ? atomicAdd(&bcur[i], c) : 0;
    }
    __syncthreads();
    for (int i = threadIdx.x; i < nb; i += 256) h[i] = 0;
    __syncthreads();
    for (int i = c0 + threadIdx.x; i < c1; i += 256) {
        int d = dstv[i];
        int b = d >> 8;
        int pos = atomicAdd(&h[b], 1);
        ebuf[base[b] + pos] = ((unsigned int)srcv[i] << 8) | (unsigned int)(d & 255);
    }
}

__global__ __launch_bounds__(256) void k_bucket(const unsigned int* __restrict__ ebuf,
                                                const int* __restrict__ bbase,
                                                int* __restrict__ rowptr,
                                                int* __restrict__ csr_src,
                                                float* __restrict__ dis, int n, int e) {
    __shared__ int cnt[256];
    __shared__ int off[256];
    int b = blockIdx.x;
    int t = threadIdx.x;
    int s0 = bbase[b], s1 = bbase[b + 1];
    cnt[t] = 0;
    __syncthreads();
    for (int i = s0 + t; i < s1; i += 256)
        atomicAdd(&cnt[ebuf[i] & 255], 1);
    __syncthreads();
    int v = cnt[t];
    off[t] = v;
    __syncthreads();
    for (int o = 1; o < 256; o <<= 1) {
        int x = (t >= o) ? off[t - o] : 0;
        __syncthreads();
        off[t] += x;
        __syncthreads();
    }
    int excl = off[t] - v;
    int node = b * 256 + t;
    if (node < n) {
        rowptr[node] = s0 + excl;
        dis[node] = rsqrtf((float)(v + 1));   // +1 self loop
    }
    if (b == 0 && t == 0) rowptr[n] = e;
    __syncthreads();
    cnt[t] = excl;   // reuse as local cursor
    __syncthreads();
    for (int i = s0 + t; i < s1; i += 256) {
        unsigned int u = ebuf[i];
        int pos = atomicAdd(&cnt[u & 255], 1);
        csr_src[s0 + pos] = (int)(u >> 8);
    }
}

// ================= W -> fp16 conversion (both layers, 8192 float4 quads) =================
__global__ __launch_bounds__(256) void k_wconv(const float* __restrict__ W1,
                                               const float* __restrict__ W2,
                                               half_t* __restrict__ Wh) {
    int q = blockIdx.x * 256 + threadIdx.x;   // 0..8191
    if (q >= 8192) return;
    const float4* src = (q < 4096) ? (const float4*)W1 : (const float4*)W2;
    float4 v = src[q & 4095];
    f16x4 h;
    h[0] = (_Float16)v.x; h[1] = (_Float16)v.y;
    h[2] = (_Float16)v.z; h[3] = (_Float16)v.w;
    ((f16x4*)Wh)[q] = h;
}

// ================= MFMA GEMM: G = (X @ W^T + b) * dis[row], fp16 in/out =================
// block 512 thr = 8 waves; tile 128 rows x 128 cols; wave -> 32 rows x 64 cols.
// A (X) staged fp16 in LDS with 16B-granule XOR swizzle; B (Wh) read from global (L2-hot).
// mfma_f32_16x16x32_f16: A lane: row=l&15, k=(l>>4)*8+0..7 ; B lane: col=l&15, same k;
// D lane: col=l&15, row=(l>>4)*4+q.
template<bool FP16IN>
__global__ __launch_bounds__(512) void k_gemm(const void* __restrict__ Xv,
                                              const half_t* __restrict__ Wh,
                                              const float* __restrict__ B,
                                              const float* __restrict__ dis,
                                              half_t* __restrict__ Gh, int n) {
    __shared__ _Float16 ldsX[128 * 128];
    const int t = threadIdx.x;
    const int row0 = blockIdx.x * 128;

    // ---- stage X tile (convert to fp16 if needed), swizzled 16B granules ----
    #pragma unroll
    for (int i = 0; i < 4; ++i) {
        int gid = i * 512 + t;          // 2048 granules = 128 rows x 16
        int row = gid >> 4, g = gid & 15;
        int grow = row0 + row;
        int so = ((g ^ (row & 7)) * 8); // swizzled half-offset in row
        f16x8 hv;
        if constexpr (FP16IN) {
            uint4 u = make_uint4(0, 0, 0, 0);
            if (grow < n) u = ((const uint4*)Xv)[(size_t)grow * 16 + g];
            hv = *(f16x8*)&u;
        } else {
            float4 a = make_float4(0.f, 0.f, 0.f, 0.f);
            float4 b = make_float4(0.f, 0.f, 0.f, 0.f);
            if (grow < n) {
                a = ((const float4*)Xv)[(size_t)grow * 32 + g * 2];
                b = ((const float4*)Xv)[(size_t)grow * 32 + g * 2 + 1];
            }
            hv[0] = (_Float16)a.x; hv[1] = (_Float16)a.y;
            hv[2] = (_Float16)a.z; hv[3] = (_Float16)a.w;
            hv[4] = (_Float16)b.x; hv[5] = (_Float16)b.y;
            hv[6] = (_Float16)b.z; hv[7] = (_Float16)b.w;
        }
        *(f16x8*)&ldsX[row * 128 + so] = hv;
    }
    __syncthreads();

    const int w = t >> 6, l = t & 63;
    const int rbase = (w >> 1) * 32;    // wave row origin (in tile)
    const int cbase = (w & 1) * 64;     // wave col origin
    const int lr = l & 15, lk = l >> 4;

    f32x4 acc[2][4] = {};

    #pragma unroll
    for (int kb = 0; kb < 4; ++kb) {
        f16x8 bf[4], af[2];
        #pragma unroll
        for (int ct = 0; ct < 4; ++ct) {
            int j = cbase + ct * 16 + lr;
            bf[ct] = *(const f16x8*)(Wh + j * 128 + kb * 32 + lk * 8);
        }
        #pragma unroll
        for (int rt = 0; rt < 2; ++rt) {
            int row = rbase + rt * 16 + lr;
            int G = kb * 4 + lk;
            af[rt] = *(const f16x8*)&ldsX[row * 128 + ((G ^ (row & 7)) * 8)];
        }
        #pragma unroll
        for (int rt = 0; rt < 2; ++rt)
            #pragma unroll
            for (int ct = 0; ct < 4; ++ct)
                acc[rt][ct] = __builtin_amdgcn_mfma_f32_16x16x32_f16(af[rt], bf[ct],
                                                                    acc[rt][ct], 0, 0, 0);
    }

    // ---- epilogue: bias + dis scale, fp16 store ----
    float bc[4];
    #pragma unroll
    for (int ct = 0; ct < 4; ++ct) bc[ct] = B[cbase + ct * 16 + lr];
    #pragma unroll
    for (int rt = 0; rt < 2; ++rt)
        #pragma unroll
        for (int q = 0; q < 4; ++q) {
            int grow = row0 + rbase + rt * 16 + lk * 4 + q;
            if (grow < n) {
                float ds = dis[grow];
                #pragma unroll
                for (int ct = 0; ct < 4; ++ct) {
                    float v = (acc[rt][ct][q] + bc[ct]) * ds;
                    Gh[(size_t)grow * 128 + cbase + ct * 16 + lr] = (_Float16)v;
                }
            }
        }
}

// ================= gather-aggregate + self loop + PReLU =================
// out[i] = prelu( dis[i] * ( G[i] + sum_{src->i} G[src] ) ), G fp16
// TWO nodes per wave: lanes 0-31 node 2p, lanes 32-63 node 2p+1; lane owns 4 cols.
template<bool FP16OUT>
__global__ __launch_bounds__(256) void k_gather(const half_t* __restrict__ G,
                                                const float* __restrict__ dis,
                                                const int* __restrict__ rowptr,
                                                const int* __restrict__ csr_src,
                                                const float* __restrict__ a,
                                                void* __restrict__ O, int n, int npair) {
    int pair = (blockIdx.x * 256 + threadIdx.x) >> 6;
    if (pair >= npair) return;
    int lane = threadIdx.x & 63;
    int half = lane >> 5;
    int cl   = lane & 31;
    int node = pair * 2 + half;
    if (node >= n) node = n - 1;

    const uint2* Gv = (const uint2*)G;
    uint2 su = Gv[(size_t)node * 32 + cl];
    float2 f0 = __half22float2(*(__half2*)&su.x);
    float2 f1 = __half22float2(*(__half2*)&su.y);
    float ax = f0.x, ay = f0.y, az = f1.x, aw = f1.y;

    int e = rowptr[node], e1 = rowptr[node + 1];
    for (; e + 4 <= e1; e += 4) {
        int s0 = csr_src[e + 0];
        int s1 = csr_src[e + 1];
        int s2 = csr_src[e + 2];
        int s3 = csr_src[e + 3];
        uint2 u0 = Gv[(size_t)s0 * 32 + cl];
        uint2 u1 = Gv[(size_t)s1 * 32 + cl];
        uint2 u2 = Gv[(size_t)s2 * 32 + cl];
        uint2 u3 = Gv[(size_t)s3 * 32 + cl];
        float2 a0 = __half22float2(*(__half2*)&u0.x), b0 = __half22float2(*(__half2*)&u0.y);
        float2 a1f = __half22float2(*(__half2*)&u1.x), b1f = __half22float2(*(__half2*)&u1.y);
        float2 a2f = __half22float2(*(__half2*)&u2.x), b2f = __half22float2(*(__half2*)&u2.y);
        float2 a3f = __half22float2(*(__half2*)&u3.x), b3f = __half22float2(*(__half2*)&u3.y);
        ax += a0.x + a1f.x + a2f.x + a3f.x;
        ay += a0.y + a1f.y + a2f.y + a3f.y;
        az += b0.x + b1f.x + b2f.x + b3f.x;
        aw += b0.y + b1f.y + b2f.y + b3f.y;
    }
    for (; e < e1; ++e) {
        int s = csr_src[e];
        uint2 u = Gv[(size_t)s * 32 + cl];
        float2 ga = __half22float2(*(__half2*)&u.x);
        float2 gb = __half22float2(*(__half2*)&u.y);
        ax += ga.x; ay += ga.y; az += gb.x; aw += gb.y;
    }

    float dsc = dis[node];
    float al = a[0];
    float vx = ax * dsc, vy = ay * dsc, vz = az * dsc, vw = aw * dsc;
    vx = vx > 0.f ? vx : al * vx;
    vy = vy > 0.f ? vy : al * vy;
    vz = vz > 0.f ? vz : al * vz;
    vw = vw > 0.f ? vw : al * vw;
    if constexpr (FP16OUT) {
        f16x4 h;
        h[0] = (_Float16)vx; h[1] = (_Float16)vy;
        h[2] = (_Float16)vz; h[3] = (_Float16)vw;
        ((f16x4*)O)[(size_t)node * 32 + cl] = h;
    } else {
        ((float4*)O)[(size_t)node * 32 + cl] = make_float4(vx, vy, vz, vw);
    }
}

extern "C" void kernel_launch(void* const* d_in, const int* in_sizes, int n_in,
                              void* d_out, int out_size, void* d_ws, size_t ws_size,
                              hipStream_t stream) {
    const float* x  = (const float*)d_in[0];
    const int*   ei = (const int*)d_in[1];
    const float* W1 = (const float*)d_in[2];
    const float* b1 = (const float*)d_in[3];
    const float* a1 = (const float*)d_in[4];
    const float* W2 = (const float*)d_in[5];
    const float* b2 = (const float*)d_in[6];
    const float* a2 = (const float*)d_in[7];

    const int n = in_sizes[0] / D;
    const int e = in_sizes[1] / 2;
    const int* srcv = ei;
    const int* dstv = ei + e;
    const int nb = (n + 255) >> 8;

    char* ws = (char*)d_ws;
    size_t off = 0;
    auto alloc = [&](size_t bytes) {
        void* p = ws + off;
        off = (off + bytes + 255) & ~(size_t)255;
        return p;
    };
    float*        dis     = (float*)       alloc((size_t)n * 4);
    int*          rowptr  = (int*)         alloc((size_t)(n + 1) * 4);
    int*          csr_src = (int*)         alloc((size_t)e * 4);
    int*          bcnt    = (int*)         alloc(512 * 4);
    int*          bbase   = (int*)         alloc(513 * 4);
    int*          bcur    = (int*)         alloc(512 * 4);
    unsigned int* ebuf    = (unsigned int*)alloc((size_t)e * 4);
    half_t*       bufH    = (half_t*)      alloc((size_t)n * D * 2);   // G (fp16)
    half_t*       h1h     = (half_t*)      alloc((size_t)n * D * 2);   // h1 (fp16)
    half_t*       Wh      = (half_t*)      alloc(2 * 16384 * 2);       // W1,W2 fp16

    dim3 blk(256);
    const int npart = (e + PCH - 1) / PCH;

    hipMemsetAsync(bcnt, 0, 512 * 4, stream);
    k_wconv <<<32, blk, 0, stream>>>(W1, W2, Wh);
    k_hist  <<<512, blk, 0, stream>>>(dstv, bcnt, e, nb);
    k_bscan <<<1, 512, 0, stream>>>(bcnt, bbase, bcur, nb, e);
    k_part  <<<npart, blk, 0, stream>>>(srcv, dstv, bcur, ebuf, e, nb);
    k_bucket<<<nb, blk, 0, stream>>>(ebuf, bbase, rowptr, csr_src, dis, n, e);

    const int npair = (n + 1) / 2;
    const int gat_grid = (npair * 64 + 255) / 256;
    const int gemm_grid = (n + 127) / 128;

    // layer 1: x(fp32) -> G1(bufH fp16) -> h1(fp16)
    k_gemm<false><<<gemm_grid, 512, 0, stream>>>(x, Wh, b1, dis, bufH, n);
    k_gather<true><<<gat_grid, blk, 0, stream>>>(bufH, dis, rowptr, csr_src, a1, h1h, n, npair);
    // layer 2: h1(fp16) -> G2(bufH fp16) -> out(fp32)
    k_gemm<true><<<gemm_grid, 512, 0, stream>>>(h1h, Wh + 16384, b2, dis, bufH, n);
    k_gather<false><<<gat_grid, blk, 0, stream>>>(bufH, dis, rowptr, csr_src, a2, d_out, n, npair);
}

// Round 9
// 256.603 us; speedup vs baseline: 22.5111x; 1.0183x over previous
//
#include <hip/hip_runtime.h>
#include <hip/hip_fp16.h>

#define D 128
#define PCH 2048   // edges per partition block

typedef _Float16 half_t;
typedef _Float16 f16x8 __attribute__((ext_vector_type(8)));
typedef _Float16 f16x4 __attribute__((ext_vector_type(4)));
typedef float    f32x4 __attribute__((ext_vector_type(4)));

// ================= bucketed CSR build (counting sort by dst>>8) =================

__global__ __launch_bounds__(256) void k_hist(const int* __restrict__ dstv, int* bcnt,
                                              int e, int nb) {
    __shared__ int h[512];
    for (int i = threadIdx.x; i < nb; i += 256) h[i] = 0;
    __syncthreads();
    int stride = gridDim.x * 256;
    for (int i = blockIdx.x * 256 + threadIdx.x; i < e; i += stride)
        atomicAdd(&h[dstv[i] >> 8], 1);
    __syncthreads();
    for (int i = threadIdx.x; i < nb; i += 256)
        if (h[i]) atomicAdd(&bcnt[i], h[i]);
}

__global__ __launch_bounds__(512) void k_bscan(const int* __restrict__ bcnt, int* bbase,
                                               int* bcur, int nb, int e) {
    __shared__ int sd[512];
    int t = threadIdx.x;
    int v = (t < nb) ? bcnt[t] : 0;
    sd[t] = v;
    __syncthreads();
    for (int off = 1; off < 512; off <<= 1) {
        int x = (t >= off) ? sd[t - off] : 0;
        __syncthreads();
        sd[t] += x;
        __syncthreads();
    }
    int excl = sd[t] - v;
    if (t < nb) { bbase[t] = excl; bcur[t] = excl; }
    if (t == nb - 1) bbase[nb] = e;
}

__global__ __launch_bounds__(256) void k_part(const int* __restrict__ srcv,
                                              const int* __restrict__ dstv,
                                              int* bcur, unsigned int* __restrict__ ebuf,
                                              int e, int nb) {
    __shared__ int h[512];
    __shared__ int base[512];
    int c0 = blockIdx.x * PCH;
    int c1 = min(c0 + PCH, e);
    for (int i = threadIdx.x; i < nb; i += 256) h[i] = 0;
    __syncthreads();
    for (int i = c0 + threadIdx.x; i < c1; i += 256)
        atomicAdd(&h[dstv[i] >> 8], 1);
    __syncthreads();
    for (int i = threadIdx.x; i < nb; i += 256) {
        int c = h[i];
        base[i] = c ? atomicAdd(&bcur[i], c) : 0;
    }
    __syncthreads();
    for (int i = threadIdx.x; i < nb; i += 256) h[i] = 0;
    __syncthreads();
    for (int i = c0 + threadIdx.x; i < c1; i += 256) {
        int d = dstv[i];
        int b = d >> 8;
        int pos = atomicAdd(&h[b], 1);
        ebuf[base[b] + pos] = ((unsigned int)srcv[i] << 8) | (unsigned int)(d & 255);
    }
}

__global__ __launch_bounds__(256) void k_bucket(const unsigned int* __restrict__ ebuf,
                                                const int* __restrict__ bbase,
                                                int* __restrict__ rowptr,
                                                int* __restrict__ csr_src,
                                                float* __restrict__ dis, int n, int e) {
    __shared__ int cnt[256];
    __shared__ int off[256];
    int b = blockIdx.x;
    int t = threadIdx.x;
    int s0 = bbase[b], s1 = bbase[b + 1];
    cnt[t] = 0;
    __syncthreads();
    for (int i = s0 + t; i < s1; i += 256)
        atomicAdd(&cnt[ebuf[i] & 255], 1);
    __syncthreads();
    int v = cnt[t];
    off[t] = v;
    __syncthreads();
    for (int o = 1; o < 256; o <<= 1) {
        int x = (t >= o) ? off[t - o] : 0;
        __syncthreads();
        off[t] += x;
        __syncthreads();
    }
    int excl = off[t] - v;
    int node = b * 256 + t;
    if (node < n) {
        rowptr[node] = s0 + excl;
        dis[node] = rsqrtf((float)(v + 1));   // +1 self loop
    }
    if (b == 0 && t == 0) rowptr[n] = e;
    __syncthreads();
    cnt[t] = excl;   // reuse as local cursor
    __syncthreads();
    for (int i = s0 + t; i < s1; i += 256) {
        unsigned int u = ebuf[i];
        int pos = atomicAdd(&cnt[u & 255], 1);
        csr_src[s0 + pos] = (int)(u >> 8);
    }
}

// ================= W -> fp16 conversion =================
__global__ __launch_bounds__(256) void k_wconv(const float* __restrict__ W1,
                                               const float* __restrict__ W2,
                                               half_t* __restrict__ Wh) {
    int q = blockIdx.x * 256 + threadIdx.x;   // 0..8191
    if (q >= 8192) return;
    const float4* src = (q < 4096) ? (const float4*)W1 : (const float4*)W2;
    float4 v = src[q & 4095];
    f16x4 h;
    h[0] = (_Float16)v.x; h[1] = (_Float16)v.y;
    h[2] = (_Float16)v.z; h[3] = (_Float16)v.w;
    ((f16x4*)Wh)[q] = h;
}

// ================= MFMA GEMM: G = (X @ W^T + b) * dis[row], fp16 in/out =================
template<bool FP16IN>
__global__ __launch_bounds__(512) void k_gemm(const void* __restrict__ Xv,
                                              const half_t* __restrict__ Wh,
                                              const float* __restrict__ B,
                                              const float* __restrict__ dis,
                                              half_t* __restrict__ Gh, int n) {
    __shared__ _Float16 ldsX[128 * 128];
    const int t = threadIdx.x;
    const int row0 = blockIdx.x * 128;

    #pragma unroll
    for (int i = 0; i < 4; ++i) {
        int gid = i * 512 + t;          // 2048 granules = 128 rows x 16
        int row = gid >> 4, g = gid & 15;
        int grow = row0 + row;
        int so = ((g ^ (row & 7)) * 8);
        f16x8 hv;
        if constexpr (FP16IN) {
            uint4 u = make_uint4(0, 0, 0, 0);
            if (grow < n) u = ((const uint4*)Xv)[(size_t)grow * 16 + g];
            hv = *(f16x8*)&u;
        } else {
            float4 a = make_float4(0.f, 0.f, 0.f, 0.f);
            float4 b = make_float4(0.f, 0.f, 0.f, 0.f);
            if (grow < n) {
                a = ((const float4*)Xv)[(size_t)grow * 32 + g * 2];
                b = ((const float4*)Xv)[(size_t)grow * 32 + g * 2 + 1];
            }
            hv[0] = (_Float16)a.x; hv[1] = (_Float16)a.y;
            hv[2] = (_Float16)a.z; hv[3] = (_Float16)a.w;
            hv[4] = (_Float16)b.x; hv[5] = (_Float16)b.y;
            hv[6] = (_Float16)b.z; hv[7] = (_Float16)b.w;
        }
        *(f16x8*)&ldsX[row * 128 + so] = hv;
    }
    __syncthreads();

    const int w = t >> 6, l = t & 63;
    const int rbase = (w >> 1) * 32;
    const int cbase = (w & 1) * 64;
    const int lr = l & 15, lk = l >> 4;

    f32x4 acc[2][4] = {};

    #pragma unroll
    for (int kb = 0; kb < 4; ++kb) {
        f16x8 bf[4], af[2];
        #pragma unroll
        for (int ct = 0; ct < 4; ++ct) {
            int j = cbase + ct * 16 + lr;
            bf[ct] = *(const f16x8*)(Wh + j * 128 + kb * 32 + lk * 8);
        }
        #pragma unroll
        for (int rt = 0; rt < 2; ++rt) {
            int row = rbase + rt * 16 + lr;
            int G = kb * 4 + lk;
            af[rt] = *(const f16x8*)&ldsX[row * 128 + ((G ^ (row & 7)) * 8)];
        }
        #pragma unroll
        for (int rt = 0; rt < 2; ++rt)
            #pragma unroll
            for (int ct = 0; ct < 4; ++ct)
                acc[rt][ct] = __builtin_amdgcn_mfma_f32_16x16x32_f16(af[rt], bf[ct],
                                                                    acc[rt][ct], 0, 0, 0);
    }

    float bc[4];
    #pragma unroll
    for (int ct = 0; ct < 4; ++ct) bc[ct] = B[cbase + ct * 16 + lr];
    #pragma unroll
    for (int rt = 0; rt < 2; ++rt)
        #pragma unroll
        for (int q = 0; q < 4; ++q) {
            int grow = row0 + rbase + rt * 16 + lk * 4 + q;
            if (grow < n) {
                float ds = dis[grow];
                #pragma unroll
                for (int ct = 0; ct < 4; ++ct) {
                    float v = (acc[rt][ct][q] + bc[ct]) * ds;
                    Gh[(size_t)grow * 128 + cbase + ct * 16 + lr] = (_Float16)v;
                }
            }
        }
}

// ================= gather-aggregate + self loop + PReLU =================
// FOUR nodes per wave: 16 lanes per node; each lane owns 8 cols (uint4 = 16 B).
// Unroll 4 -> 16 row-loads in flight per wave.
template<bool FP16OUT>
__global__ __launch_bounds__(256) void k_gather(const half_t* __restrict__ G,
                                                const float* __restrict__ dis,
                                                const int* __restrict__ rowptr,
                                                const int* __restrict__ csr_src,
                                                const float* __restrict__ a,
                                                void* __restrict__ O, int n, int nquad) {
    int wq = (blockIdx.x * 256 + threadIdx.x) >> 6;
    if (wq >= nquad) return;
    int lane = threadIdx.x & 63;
    int node = wq * 4 + (lane >> 4);
    if (node >= n) node = n - 1;   // duplicate last node (identical writes)
    int sl = lane & 15;            // column octet 0..15

    const uint4* Gv = (const uint4*)G;   // one uint4 = 8 halves
    float ac[8];
    {
        uint4 su = Gv[(size_t)node * 16 + sl];
        f16x8 h = *(f16x8*)&su;
        #pragma unroll
        for (int j = 0; j < 8; ++j) ac[j] = (float)h[j];
    }

    int e = rowptr[node], e1 = rowptr[node + 1];
    for (; e + 4 <= e1; e += 4) {
        int s0 = csr_src[e + 0];
        int s1 = csr_src[e + 1];
        int s2 = csr_src[e + 2];
        int s3 = csr_src[e + 3];
        uint4 u0 = Gv[(size_t)s0 * 16 + sl];
        uint4 u1 = Gv[(size_t)s1 * 16 + sl];
        uint4 u2 = Gv[(size_t)s2 * 16 + sl];
        uint4 u3 = Gv[(size_t)s3 * 16 + sl];
        f16x8 h0 = *(f16x8*)&u0;
        f16x8 h1 = *(f16x8*)&u1;
        f16x8 h2 = *(f16x8*)&u2;
        f16x8 h3 = *(f16x8*)&u3;
        #pragma unroll
        for (int j = 0; j < 8; ++j)
            ac[j] += (float)h0[j] + (float)h1[j] + (float)h2[j] + (float)h3[j];
    }
    for (; e < e1; ++e) {
        int s = csr_src[e];
        uint4 u = Gv[(size_t)s * 16 + sl];
        f16x8 h = *(f16x8*)&u;
        #pragma unroll
        for (int j = 0; j < 8; ++j) ac[j] += (float)h[j];
    }

    float dsc = dis[node];
    float al = a[0];
    #pragma unroll
    for (int j = 0; j < 8; ++j) {
        float v = ac[j] * dsc;
        ac[j] = v > 0.f ? v : al * v;
    }
    if constexpr (FP16OUT) {
        f16x8 h;
        #pragma unroll
        for (int j = 0; j < 8; ++j) h[j] = (_Float16)ac[j];
        ((f16x8*)O)[(size_t)node * 16 + sl] = h;
    } else {
        float4 o0 = make_float4(ac[0], ac[1], ac[2], ac[3]);
        float4 o1 = make_float4(ac[4], ac[5], ac[6], ac[7]);
        ((float4*)O)[(size_t)node * 32 + sl * 2]     = o0;
        ((float4*)O)[(size_t)node * 32 + sl * 2 + 1] = o1;
    }
}

extern "C" void kernel_launch(void* const* d_in, const int* in_sizes, int n_in,
                              void* d_out, int out_size, void* d_ws, size_t ws_size,
                              hipStream_t stream) {
    const float* x  = (const float*)d_in[0];
    const int*   ei = (const int*)d_in[1];
    const float* W1 = (const float*)d_in[2];
    const float* b1 = (const float*)d_in[3];
    const float* a1 = (const float*)d_in[4];
    const float* W2 = (const float*)d_in[5];
    const float* b2 = (const float*)d_in[6];
    const float* a2 = (const float*)d_in[7];

    const int n = in_sizes[0] / D;
    const int e = in_sizes[1] / 2;
    const int* srcv = ei;
    const int* dstv = ei + e;
    const int nb = (n + 255) >> 8;

    char* ws = (char*)d_ws;
    size_t off = 0;
    auto alloc = [&](size_t bytes) {
        void* p = ws + off;
        off = (off + bytes + 255) & ~(size_t)255;
        return p;
    };
    float*        dis     = (float*)       alloc((size_t)n * 4);
    int*          rowptr  = (int*)         alloc((size_t)(n + 1) * 4);
    int*          csr_src = (int*)         alloc((size_t)e * 4);
    int*          bcnt    = (int*)         alloc(512 * 4);
    int*          bbase   = (int*)         alloc(513 * 4);
    int*          bcur    = (int*)         alloc(512 * 4);
    unsigned int* ebuf    = (unsigned int*)alloc((size_t)e * 4);
    half_t*       bufH    = (half_t*)      alloc((size_t)n * D * 2);   // G (fp16)
    half_t*       h1h     = (half_t*)      alloc((size_t)n * D * 2);   // h1 (fp16)
    half_t*       Wh      = (half_t*)      alloc(2 * 16384 * 2);       // W1,W2 fp16

    dim3 blk(256);
    const int npart = (e + PCH - 1) / PCH;

    hipMemsetAsync(bcnt, 0, 512 * 4, stream);
    k_wconv <<<32, blk, 0, stream>>>(W1, W2, Wh);
    k_hist  <<<512, blk, 0, stream>>>(dstv, bcnt, e, nb);
    k_bscan <<<1, 512, 0, stream>>>(bcnt, bbase, bcur, nb, e);
    k_part  <<<npart, blk, 0, stream>>>(srcv, dstv, bcur, ebuf, e, nb);
    k_bucket<<<nb, blk, 0, stream>>>(ebuf, bbase, rowptr, csr_src, dis, n, e);

    const int nquad = (n + 3) / 4;
    const int gat_grid = (nquad * 64 + 255) / 256;
    const int gemm_grid = (n + 127) / 128;

    // layer 1: x(fp32) -> G1(bufH fp16) -> h1(fp16)
    k_gemm<false><<<gemm_grid, 512, 0, stream>>>(x, Wh, b1, dis, bufH, n);
    k_gather<true><<<gat_grid, blk, 0, stream>>>(bufH, dis, rowptr, csr_src, a1, h1h, n, nquad);
    // layer 2: h1(fp16) -> G2(bufH fp16) -> out(fp32)
    k_gemm<true><<<gemm_grid, 512, 0, stream>>>(h1h, Wh + 16384, b2, dis, bufH, n);
    k_gather<false><<<gat_grid, blk, 0, stream>>>(bufH, dis, rowptr, csr_src, a2, d_out, n, nquad);
}

// Round 10
// 237.676 us; speedup vs baseline: 24.3037x; 1.0796x over previous
//
#include <hip/hip_runtime.h>
#include <hip/hip_fp16.h>

#define D 128
#define PCH 4096   // edges per partition block

typedef _Float16 half_t;
typedef _Float16 f16x8 __attribute__((ext_vector_type(8)));
typedef _Float16 f16x4 __attribute__((ext_vector_type(4)));
typedef float    f32x4 __attribute__((ext_vector_type(4)));

// ================= hist (blocks 0..511) + W->fp16 conversion (blocks 512..543) =================
__global__ __launch_bounds__(256) void k_histw(const int* __restrict__ dstv, int* bcnt,
                                               int e, int nb,
                                               const float* __restrict__ W1,
                                               const float* __restrict__ W2,
                                               half_t* __restrict__ Wh) {
    if (blockIdx.x >= 512) {
        int q = (blockIdx.x - 512) * 256 + threadIdx.x;   // 0..8191
        if (q < 8192) {
            const float4* src = (q < 4096) ? (const float4*)W1 : (const float4*)W2;
            float4 v = src[q & 4095];
            f16x4 h;
            h[0] = (_Float16)v.x; h[1] = (_Float16)v.y;
            h[2] = (_Float16)v.z; h[3] = (_Float16)v.w;
            ((f16x4*)Wh)[q] = h;
        }
        return;
    }
    __shared__ int h[512];
    for (int i = threadIdx.x; i < nb; i += 256) h[i] = 0;
    __syncthreads();
    const int stride = 512 * 256;
    for (int i = blockIdx.x * 256 + threadIdx.x; i < e; i += stride)
        atomicAdd(&h[dstv[i] >> 8], 1);
    __syncthreads();
    for (int i = threadIdx.x; i < nb; i += 256)
        if (h[i]) atomicAdd(&bcnt[i], h[i]);
}

__global__ __launch_bounds__(512) void k_bscan(const int* __restrict__ bcnt, int* bbase,
                                               int* bcur, int nb, int e) {
    __shared__ int sd[512];
    int t = threadIdx.x;
    int v = (t < nb) ? bcnt[t] : 0;
    sd[t] = v;
    __syncthreads();
    for (int off = 1; off < 512; off <<= 1) {
        int x = (t >= off) ? sd[t - off] : 0;
        __syncthreads();
        sd[t] += x;
        __syncthreads();
    }
    int excl = sd[t] - v;
    if (t < nb) { bbase[t] = excl; bcur[t] = excl; }
    if (t == nb - 1) bbase[nb] = e;
}

// partition edges into bucket-contiguous ebuf, packed (src<<8)|(dst&255)
__global__ __launch_bounds__(512) void k_part(const int* __restrict__ srcv,
                                              const int* __restrict__ dstv,
                                              int* bcur, unsigned int* __restrict__ ebuf,
                                              int e, int nb) {
    __shared__ int h[512];
    __shared__ int base[512];
    int c0 = blockIdx.x * PCH;
    int c1 = min(c0 + PCH, e);
    for (int i = threadIdx.x; i < nb; i += 512) h[i] = 0;
    __syncthreads();
    for (int i = c0 + threadIdx.x; i < c1; i += 512)
        atomicAdd(&h[dstv[i] >> 8], 1);
    __syncthreads();
    for (int i = threadIdx.x; i < nb; i += 512) {
        int c = h[i];
        base[i] = c ? atomicAdd(&bcur[i], c) : 0;
    }
    __syncthreads();
    for (int i = threadIdx.x; i < nb; i += 512) h[i] = 0;
    __syncthreads();
    for (int i = c0 + threadIdx.x; i < c1; i += 512) {
        int d = dstv[i];
        int b = d >> 8;
        int pos = atomicAdd(&h[b], 1);
        ebuf[base[b] + pos] = ((unsigned int)srcv[i] << 8) | (unsigned int)(d & 255);
    }
}

// per-bucket: local count -> rowptr + dis, then fill csr_src (contiguous slice)
__global__ __launch_bounds__(512) void k_bucket(const unsigned int* __restrict__ ebuf,
                                                const int* __restrict__ bbase,
                                                int* __restrict__ rowptr,
                                                int* __restrict__ csr_src,
                                                float* __restrict__ dis, int n, int e) {
    __shared__ int cnt[256];
    __shared__ int off[256];
    int b = blockIdx.x;
    int t = threadIdx.x;
    int s0 = bbase[b], s1 = bbase[b + 1];
    if (t < 256) cnt[t] = 0;
    __syncthreads();
    for (int i = s0 + t; i < s1; i += 512)
        atomicAdd(&cnt[ebuf[i] & 255], 1);
    __syncthreads();
    int v = (t < 256) ? cnt[t] : 0;
    if (t < 256) off[t] = v;
    __syncthreads();
    for (int o = 1; o < 256; o <<= 1) {
        int x = (t >= o && t < 256) ? off[t - o] : 0;
        __syncthreads();
        if (t < 256) off[t] += x;
        __syncthreads();
    }
    if (t < 256) {
        int excl = off[t] - v;
        int node = b * 256 + t;
        if (node < n) {
            rowptr[node] = s0 + excl;
            dis[node] = rsqrtf((float)(v + 1));   // +1 self loop
        }
        if (b == 0 && t == 0) rowptr[n] = e;
        cnt[t] = excl;   // reuse as local cursor
    }
    __syncthreads();
    for (int i = s0 + t; i < s1; i += 512) {
        unsigned int u = ebuf[i];
        int pos = atomicAdd(&cnt[u & 255], 1);
        csr_src[s0 + pos] = (int)(u >> 8);
    }
}

// ================= MFMA GEMM: G = (X @ W^T + b) * dis[row], fp16 in/out =================
// block 512 thr = 8 waves; tile 128 rows x 128 cols; wave -> 32 rows x 64 cols.
// A (X) staged fp16 in LDS (XOR-swizzled 16B granules); B (Wh) from global (L2-hot).
// Epilogue repacks through LDS for coalesced f16x8 global stores.
template<bool FP16IN>
__global__ __launch_bounds__(512) void k_gemm(const void* __restrict__ Xv,
                                              const half_t* __restrict__ Wh,
                                              const float* __restrict__ B,
                                              const float* __restrict__ dis,
                                              half_t* __restrict__ Gh, int n) {
    __shared__ _Float16 lds[128 * 136];   // X-stage (stride 128), then O-stage (stride 136)
    const int t = threadIdx.x;
    const int row0 = blockIdx.x * 128;

    // ---- stage X tile (fp16), swizzled 16B granules ----
    #pragma unroll
    for (int i = 0; i < 4; ++i) {
        int gid = i * 512 + t;          // 2048 granules = 128 rows x 16
        int row = gid >> 4, g = gid & 15;
        int grow = row0 + row;
        int so = ((g ^ (row & 7)) * 8);
        f16x8 hv;
        if constexpr (FP16IN) {
            uint4 u = make_uint4(0, 0, 0, 0);
            if (grow < n) u = ((const uint4*)Xv)[(size_t)grow * 16 + g];
            hv = *(f16x8*)&u;
        } else {
            float4 a = make_float4(0.f, 0.f, 0.f, 0.f);
            float4 b = make_float4(0.f, 0.f, 0.f, 0.f);
            if (grow < n) {
                a = ((const float4*)Xv)[(size_t)grow * 32 + g * 2];
                b = ((const float4*)Xv)[(size_t)grow * 32 + g * 2 + 1];
            }
            hv[0] = (_Float16)a.x; hv[1] = (_Float16)a.y;
            hv[2] = (_Float16)a.z; hv[3] = (_Float16)a.w;
            hv[4] = (_Float16)b.x; hv[5] = (_Float16)b.y;
            hv[6] = (_Float16)b.z; hv[7] = (_Float16)b.w;
        }
        *(f16x8*)&lds[row * 128 + so] = hv;
    }
    __syncthreads();

    const int w = t >> 6, l = t & 63;
    const int rbase = (w >> 1) * 32;
    const int cbase = (w & 1) * 64;
    const int lr = l & 15, lk = l >> 4;

    f32x4 acc[2][4] = {};

    #pragma unroll
    for (int kb = 0; kb < 4; ++kb) {
        f16x8 bf[4], af[2];
        #pragma unroll
        for (int ct = 0; ct < 4; ++ct) {
            int j = cbase + ct * 16 + lr;
            bf[ct] = *(const f16x8*)(Wh + j * 128 + kb * 32 + lk * 8);
        }
        #pragma unroll
        for (int rt = 0; rt < 2; ++rt) {
            int row = rbase + rt * 16 + lr;
            int G = kb * 4 + lk;
            af[rt] = *(const f16x8*)&lds[row * 128 + ((G ^ (row & 7)) * 8)];
        }
        #pragma unroll
        for (int rt = 0; rt < 2; ++rt)
            #pragma unroll
            for (int ct = 0; ct < 4; ++ct)
                acc[rt][ct] = __builtin_amdgcn_mfma_f32_16x16x32_f16(af[rt], bf[ct],
                                                                    acc[rt][ct], 0, 0, 0);
    }

    // ---- epilogue: bias + dis scale -> LDS repack -> coalesced fp16 store ----
    float bc[4];
    #pragma unroll
    for (int ct = 0; ct < 4; ++ct) bc[ct] = B[cbase + ct * 16 + lr];

    __syncthreads();   // all fragment reads of lds done; safe to overwrite
    #pragma unroll
    for (int rt = 0; rt < 2; ++rt)
        #pragma unroll
        for (int q = 0; q < 4; ++q) {
            int rl = rbase + rt * 16 + lk * 4 + q;
            int grow = row0 + rl;
            float ds = (grow < n) ? dis[grow] : 0.f;
            #pragma unroll
            for (int ct = 0; ct < 4; ++ct) {
                float v = (acc[rt][ct][q] + bc[ct]) * ds;
                lds[rl * 136 + cbase + ct * 16 + lr] = (_Float16)v;
            }
        }
    __syncthreads();
    #pragma unroll
    for (int i = 0; i < 4; ++i) {
        int gid = i * 512 + t;
        int row = gid >> 4, g = gid & 15;
        int grow = row0 + row;
        if (grow < n)
            *(f16x8*)&Gh[(size_t)grow * 128 + g * 8] = *(f16x8*)&lds[row * 136 + g * 8];
    }
}

// ================= gather-aggregate + self loop + PReLU =================
// FOUR nodes per wave: 16 lanes per node; each lane owns 8 cols (uint4 = 16 B).
template<bool FP16OUT>
__global__ __launch_bounds__(256) void k_gather(const half_t* __restrict__ G,
                                                const float* __restrict__ dis,
                                                const int* __restrict__ rowptr,
                                                const int* __restrict__ csr_src,
                                                const float* __restrict__ a,
                                                void* __restrict__ O, int n, int nquad) {
    int wq = (blockIdx.x * 256 + threadIdx.x) >> 6;
    if (wq >= nquad) return;
    int lane = threadIdx.x & 63;
    int node = wq * 4 + (lane >> 4);
    if (node >= n) node = n - 1;   // duplicate last node (identical writes)
    int sl = lane & 15;            // column octet 0..15

    const uint4* Gv = (const uint4*)G;   // one uint4 = 8 halves
    float ac[8];
    {
        uint4 su = Gv[(size_t)node * 16 + sl];
        f16x8 h = *(f16x8*)&su;
        #pragma unroll
        for (int j = 0; j < 8; ++j) ac[j] = (float)h[j];
    }

    int e = rowptr[node], e1 = rowptr[node + 1];
    for (; e + 4 <= e1; e += 4) {
        int s0 = csr_src[e + 0];
        int s1 = csr_src[e + 1];
        int s2 = csr_src[e + 2];
        int s3 = csr_src[e + 3];
        uint4 u0 = Gv[(size_t)s0 * 16 + sl];
        uint4 u1 = Gv[(size_t)s1 * 16 + sl];
        uint4 u2 = Gv[(size_t)s2 * 16 + sl];
        uint4 u3 = Gv[(size_t)s3 * 16 + sl];
        f16x8 h0 = *(f16x8*)&u0;
        f16x8 h1 = *(f16x8*)&u1;
        f16x8 h2 = *(f16x8*)&u2;
        f16x8 h3 = *(f16x8*)&u3;
        #pragma unroll
        for (int j = 0; j < 8; ++j)
            ac[j] += (float)h0[j] + (float)h1[j] + (float)h2[j] + (float)h3[j];
    }
    for (; e < e1; ++e) {
        int s = csr_src[e];
        uint4 u = Gv[(size_t)s * 16 + sl];
        f16x8 h = *(f16x8*)&u;
        #pragma unroll
        for (int j = 0; j < 8; ++j) ac[j] += (float)h[j];
    }

    float dsc = dis[node];
    float al = a[0];
    #pragma unroll
    for (int j = 0; j < 8; ++j) {
        float v = ac[j] * dsc;
        ac[j] = v > 0.f ? v : al * v;
    }
    if constexpr (FP16OUT) {
        f16x8 h;
        #pragma unroll
        for (int j = 0; j < 8; ++j) h[j] = (_Float16)ac[j];
        ((f16x8*)O)[(size_t)node * 16 + sl] = h;
    } else {
        float4 o0 = make_float4(ac[0], ac[1], ac[2], ac[3]);
        float4 o1 = make_float4(ac[4], ac[5], ac[6], ac[7]);
        ((float4*)O)[(size_t)node * 32 + sl * 2]     = o0;
        ((float4*)O)[(size_t)node * 32 + sl * 2 + 1] = o1;
    }
}

extern "C" void kernel_launch(void* const* d_in, const int* in_sizes, int n_in,
                              void* d_out, int out_size, void* d_ws, size_t ws_size,
                              hipStream_t stream) {
    const float* x  = (const float*)d_in[0];
    const int*   ei = (const int*)d_in[1];
    const float* W1 = (const float*)d_in[2];
    const float* b1 = (const float*)d_in[3];
    const float* a1 = (const float*)d_in[4];
    const float* W2 = (const float*)d_in[5];
    const float* b2 = (const float*)d_in[6];
    const float* a2 = (const float*)d_in[7];

    const int n = in_sizes[0] / D;
    const int e = in_sizes[1] / 2;
    const int* srcv = ei;
    const int* dstv = ei + e;
    const int nb = (n + 255) >> 8;

    char* ws = (char*)d_ws;
    size_t off = 0;
    auto alloc = [&](size_t bytes) {
        void* p = ws + off;
        off = (off + bytes + 255) & ~(size_t)255;
        return p;
    };
    float*        dis     = (float*)       alloc((size_t)n * 4);
    int*          rowptr  = (int*)         alloc((size_t)(n + 1) * 4);
    int*          csr_src = (int*)         alloc((size_t)e * 4);
    int*          bcnt    = (int*)         alloc(512 * 4);
    int*          bbase   = (int*)         alloc(513 * 4);
    int*          bcur    = (int*)         alloc(512 * 4);
    unsigned int* ebuf    = (unsigned int*)alloc((size_t)e * 4);
    half_t*       bufH    = (half_t*)      alloc((size_t)n * D * 2);   // G (fp16)
    half_t*       h1h     = (half_t*)      alloc((size_t)n * D * 2);   // h1 (fp16)
    half_t*       Wh      = (half_t*)      alloc(2 * 16384 * 2);       // W1,W2 fp16

    dim3 blk(256);
    const int npart = (e + PCH - 1) / PCH;

    hipMemsetAsync(bcnt, 0, 512 * 4, stream);
    k_histw <<<544, blk, 0, stream>>>(dstv, bcnt, e, nb, W1, W2, Wh);
    k_bscan <<<1, 512, 0, stream>>>(bcnt, bbase, bcur, nb, e);
    k_part  <<<npart, 512, 0, stream>>>(srcv, dstv, bcur, ebuf, e, nb);
    k_bucket<<<nb, 512, 0, stream>>>(ebuf, bbase, rowptr, csr_src, dis, n, e);

    const int nquad = (n + 3) / 4;
    const int gat_grid = (nquad * 64 + 255) / 256;
    const int gemm_grid = (n + 127) / 128;

    // layer 1: x(fp32) -> G1(bufH fp16) -> h1(fp16)
    k_gemm<false><<<gemm_grid, 512, 0, stream>>>(x, Wh, b1, dis, bufH, n);
    k_gather<true><<<gat_grid, blk, 0, stream>>>(bufH, dis, rowptr, csr_src, a1, h1h, n, nquad);
    // layer 2: h1(fp16) -> G2(bufH fp16) -> out(fp32)
    k_gemm<true><<<gemm_grid, 512, 0, stream>>>(h1h, Wh + 16384, b2, dis, bufH, n);
    k_gather<false><<<gat_grid, blk, 0, stream>>>(bufH, dis, rowptr, csr_src, a2, d_out, n, nquad);
}